// Round 14
// baseline (491.115 us; speedup 1.0000x reference)
//
#include <hip/hip_runtime.h>
#include <hip/hip_bf16.h>
#include <math.h>

#define BDIM 1024
#define TDIM 4096
#define BT   16384   // B*T
#define KEXPN 8
#define RRANK 64
#define KR   512     // KEXPN*RRANK
#define PW2  1152    // packed P width: 512 prod_f + 512 prod_i + 8 wf + 8 wi + 112 pad
#define KRC  1024    // concatenated xV/yW width
#define NCH  64
#define TC   64      // T per chunk (NCH*TC == TDIM)

typedef __attribute__((ext_vector_type(8))) short bf16x8;
typedef __attribute__((ext_vector_type(4))) float f32x4;

typedef __attribute__((address_space(1))) char g_char;
typedef __attribute__((address_space(3))) char l_char;

// async 16B global->LDS: per-lane global addr, wave-uniform LDS base (+lane*16 by HW)
__device__ __forceinline__ void gload16(const short* g, short* lds_base_uniform) {
  __builtin_amdgcn_global_load_lds((const g_char*)(const char*)g,
                                   (l_char*)(char*)lds_base_uniform, 16, 0, 0);
}

// ---------------- elementwise conversion f32 -> bf16 (vectorized x4) ----------------
__global__ __launch_bounds__(256) void cvt_bf16_kernel(const float* __restrict__ in,
    __hip_bfloat16* __restrict__ out, long n4) {
  long id = (long)blockIdx.x * 256 + threadIdx.x;
  if (id >= n4) return;
  f32x4 v = ((const f32x4*)in)[id];
  long i = id * 4;
  out[i + 0] = __float2bfloat16(v[0]);
  out[i + 1] = __float2bfloat16(v[1]);
  out[i + 2] = __float2bfloat16(v[2]);
  out[i + 3] = __float2bfloat16(v[3]);
}

// ---------------- merged transpose-pack x3: out[e][d] = in[d][e], D x D ----------------
__global__ __launch_bounds__(256) void transpose3_kernel(
    const float* __restrict__ in0, __hip_bfloat16* __restrict__ o0,
    const float* __restrict__ in1, __hip_bfloat16* __restrict__ o1,
    const float* __restrict__ in2, __hip_bfloat16* __restrict__ o2) {
  int id = blockIdx.x * 256 + threadIdx.x;
  if (id >= BDIM * BDIM) return;
  const float* in = blockIdx.y == 0 ? in0 : (blockIdx.y == 1 ? in1 : in2);
  __hip_bfloat16* out = blockIdx.y == 0 ? o0 : (blockIdx.y == 1 ? o1 : o2);
  int d = id & (BDIM - 1);
  int e = id >> 10;
  out[(size_t)e * BDIM + d] = __float2bfloat16(in[(size_t)d * BDIM + e]);
}

// ---------------- merged pack V x4: (K,D,R) -> [(k*64+r)][d] bf16 ----------------
__global__ __launch_bounds__(256) void vmat4_kernel(
    const float* __restrict__ i0, __hip_bfloat16* __restrict__ o0,
    const float* __restrict__ i1, __hip_bfloat16* __restrict__ o1,
    const float* __restrict__ i2, __hip_bfloat16* __restrict__ o2,
    const float* __restrict__ i3, __hip_bfloat16* __restrict__ o3) {
  int id = blockIdx.x * 256 + threadIdx.x;
  if (id >= KR * BDIM) return;
  const float* V = blockIdx.y == 0 ? i0 : (blockIdx.y == 1 ? i1 : (blockIdx.y == 2 ? i2 : i3));
  __hip_bfloat16* out = blockIdx.y == 0 ? o0 : (blockIdx.y == 1 ? o1 : (blockIdx.y == 2 ? o2 : o3));
  int d = id & (BDIM - 1);
  int kr = id >> 10;
  int k = kr >> 6, r = kr & 63;
  out[(size_t)kr * BDIM + d] = __float2bfloat16(V[((size_t)k * BDIM + d) * RRANK + r]);
}

// ---------------- pack UTT[c][e], c in [0,1152): Uf-prod | Ui-prod | bf | bi | zeros ----------------
__global__ __launch_bounds__(256) void utt_pack_kernel(
    const float* __restrict__ Uf, const float* __restrict__ bf,
    const float* __restrict__ Ui, const float* __restrict__ bi,
    __hip_bfloat16* __restrict__ out) {
  int id = blockIdx.x * 256 + threadIdx.x;
  if (id >= PW2 * BDIM) return;
  int e = id & (BDIM - 1);
  int c = id >> 10;
  float v = 0.0f;
  if (c < KR) {
    int k = c >> 6, r = c & 63;
    v = Uf[((size_t)k * BDIM + e) * RRANK + r];
  } else if (c < 2 * KR) {
    int c2 = c - KR;
    int k = c2 >> 6, r = c2 & 63;
    v = Ui[((size_t)k * BDIM + e) * RRANK + r];
  } else if (c < 2 * KR + KEXPN) {
    v = bf[(size_t)(c - 2 * KR) * BDIM + e];
  } else if (c < 2 * KR + 2 * KEXPN) {
    v = bi[(size_t)(c - 2 * KR - KEXPN) * BDIM + e];
  }
  out[(size_t)c * BDIM + e] = __float2bfloat16(v);
}

// ================= 128^2 2-phase fold engine, TWO parallel partitions per launch =================
struct FoldArgs {
  const __hip_bfloat16* A; const __hip_bfloat16* B;
  void* C1; void* C2; void* C3;
  int rs1, rs2, ldc, M, N, Kd;
};

__device__ __forceinline__ void fold_body(const FoldArgs fa, int bx, int by,
                                          short* Als, short* Bls) {
  const short* As = (const short*)fa.A;
  const short* Bs = (const short*)fa.B;
  const int Kd = fa.Kd;
  const int t  = threadIdx.x;
  const int w  = t >> 6;
  const int l  = t & 63;
  const int lr = l & 15;
  const int lk = l >> 4;
  const int wr = w >> 1;
  const int wc = w & 1;
  const int row0 = by * 128;
  const int col0 = bx * 128;
  const int srow = w * 16 + (l >> 2);
  const int scol = (l & 3) * 8;
  const short* ag0 = As + (size_t)(row0 + srow) * Kd + scol;
  const short* ag1 = As + (size_t)(row0 + 64 + srow) * Kd + scol;
  const short* bg0 = Bs + (size_t)(col0 + srow) * Kd + scol;
  const short* bg1 = Bs + (size_t)(col0 + 64 + srow) * Kd + scol;
  f32x4 acc[4][4] = {};
  const int nt = Kd / 32;
  auto stage = [&](int kt, int buf) {
    int k0 = kt * 32;
    gload16(ag0 + k0, Als + buf * 4096 + w * 512);
    gload16(ag1 + k0, Als + buf * 4096 + 2048 + w * 512);
    gload16(bg0 + k0, Bls + buf * 4096 + w * 512);
    gload16(bg1 + k0, Bls + buf * 4096 + 2048 + w * 512);
  };
  stage(0, 0);
  __syncthreads();
  int cur = 0;
  for (int kt = 0; kt < nt; ++kt) {
    if (kt + 1 < nt) stage(kt + 1, cur ^ 1);
    bf16x8 af[4], bfr[4];
    #pragma unroll
    for (int i = 0; i < 4; i++)
      af[i] = *(const bf16x8*)&Als[cur * 4096 + (wr * 64 + i * 16 + lr) * 32 + lk * 8];
    #pragma unroll
    for (int j = 0; j < 4; j++)
      bfr[j] = *(const bf16x8*)&Bls[cur * 4096 + (wc * 64 + j * 16 + lr) * 32 + lk * 8];
    #pragma unroll
    for (int i = 0; i < 4; i++)
      #pragma unroll
      for (int j = 0; j < 4; j++)
        acc[i][j] = __builtin_amdgcn_mfma_f32_16x16x32_bf16(af[i], bfr[j], acc[i][j], 0, 0, 0);
    __syncthreads();
    cur ^= 1;
  }
  #pragma unroll
  for (int i = 0; i < 4; i++)
    #pragma unroll
    for (int j = 0; j < 4; j++)
      #pragma unroll
      for (int g = 0; g < 4; g++) {
        int r = row0 + wr * 64 + i * 16 + lk * 4 + g;
        int c = col0 + wc * 64 + j * 16 + lr;
        void* dst = fa.C1; int rr = r;
        if (r >= fa.rs2)      { dst = fa.C3; rr = r - fa.rs2; }
        else if (r >= fa.rs1) { dst = fa.C2; rr = r - fa.rs1; }
        ((__hip_bfloat16*)dst)[(size_t)rr * fa.ldc + c] = __float2bfloat16(acc[i][j][g]);
      }
}

__global__ __launch_bounds__(256) void gemm_fold2(FoldArgs fa0, FoldArgs fa1, int nblk0) {
  __shared__ __align__(16) short Als[2 * 128 * 32];
  __shared__ __align__(16) short Bls[2 * 128 * 32];
  int id = blockIdx.x;
  if (id < nblk0) {
    int nbx = fa0.N / 128;
    fold_body(fa0, id % nbx, id / nbx, Als, Bls);
  } else {
    int lid = id - nblk0;
    int nbx = fa1.N / 128;
    fold_body(fa1, lid % nbx, lid / nbx, Als, Bls);
  }
}

// ================= 256^2 4-phase BK=64 engine with COUNTED vmcnt (T4) =================
// Per-half staging ledger: ph1 stages kt+1 kh0 (4 loads), ph2 stages kt+1 kh1 (4).
// Waits: after ph2 MFMA vmcnt(8) (kh1(kt) landed; 8 newer loads fly);
//        after ph4 MFMA vmcnt(4) (kh0(kt+1) landed; kh1(kt+1) flies). Never 0 in steady state.
// EPI: 2 = bias+GELU->bf16 (2-seg), 4 = /n_valid->f32, 5 = 4-seg merged (gelu|gelu|bf16|bf16)
template<int EPI>
__global__ __launch_bounds__(512, 2) void gemm_nt_256(const __hip_bfloat16* __restrict__ A,
    const __hip_bfloat16* __restrict__ B, void* __restrict__ Cv, void* __restrict__ Cv2,
    void* __restrict__ Cv3, void* __restrict__ Cv4,
    int csplit, int ldc, int ldc2, const float* __restrict__ bias, int M, int N, int Kd) {
  __shared__ __align__(16) short Als[2][2][256 * 32];   // [buf][kh] 64 KB
  __shared__ __align__(16) short Bls[2][2][256 * 32];   // 64 KB

  int nbx = gridDim.x;
  int nwg = nbx * gridDim.y;
  int bx = blockIdx.x, by = blockIdx.y;
  if ((nwg & 7) == 0) {
    int orig = by * nbx + bx;
    int cpx = nwg >> 3;
    int id = (orig & 7) * cpx + (orig >> 3);
    bx = id % nbx; by = id / nbx;
  }
  const short* As = (const short*)A;
  const short* Bs = (const short*)B;
  const int t  = threadIdx.x;      // 0..511
  const int w  = t >> 6;           // 0..7
  const int l  = t & 63;
  const int lr = l & 15;
  const int lk = l >> 4;
  const int wr = w >> 2;           // 0..1 (M half)
  const int wc = w & 3;            // 0..3 (N quarter)
  const int row0 = by * 256;
  const int col0 = bx * 256;

  const int srow  = t >> 2;                       // 0..127
  const int sslot = (t & 3) ^ ((srow >> 1) & 3);
  const short* agA0 = As + (size_t)(row0 + srow) * Kd + sslot * 8;
  const short* agA1 = As + (size_t)(row0 + 128 + srow) * Kd + sslot * 8;
  const short* bgB0 = Bs + (size_t)(col0 + srow) * Kd + sslot * 8;
  const short* bgB1 = Bs + (size_t)(col0 + 128 + srow) * Kd + sslot * 8;

  // stage one K-half (A + B) of tile kt into buf: 4 load instructions
  auto stage_half = [&](int buf, int kh, int kt) {
    int k0 = kt * 64 + kh * 32;
    short* ab = &Als[buf][kh][0];
    short* bb = &Bls[buf][kh][0];
    gload16(agA0 + k0, ab + w * 512);
    gload16(agA1 + k0, ab + 4096 + w * 512);
    gload16(bgB0 + k0, bb + w * 512);
    gload16(bgB1 + k0, bb + 4096 + w * 512);
  };

  int aoff[8], boff[4];
  #pragma unroll
  for (int mf = 0; mf < 8; ++mf) {
    int r = wr * 128 + mf * 16 + lr;
    aoff[mf] = r * 32 + ((lk ^ ((r >> 1) & 3)) << 3);
  }
  #pragma unroll
  for (int nf = 0; nf < 4; ++nf) {
    int r = wc * 64 + nf * 16 + lr;
    boff[nf] = r * 32 + ((lk ^ ((r >> 1) & 3)) << 3);
  }

  f32x4 acc[8][4] = {};
  const int NT = Kd >> 6;   // K-tiles of 64

  // prologue: stage tile 0 (kh0 then kh1); wait kh0 only (kh1 stays in flight)
  stage_half(0, 0, 0);
  stage_half(0, 1, 0);
  asm volatile("s_waitcnt vmcnt(4)" ::: "memory");
  __builtin_amdgcn_sched_barrier(0);
  __builtin_amdgcn_s_barrier();

  for (int kt = 0; kt < NT; ++kt) {
    const int buf = kt & 1, nb = buf ^ 1;
    const short* A0 = &Als[buf][0][0];
    const short* A1 = &Als[buf][1][0];
    const short* B0 = &Bls[buf][0][0];
    const short* B1 = &Bls[buf][1][0];
    const bool st = (kt + 1 < NT);
    bf16x8 af[4], bfr[4];

    // ---- phase 1: kh0, M-half 0; stage kt+1 kh0 ----
    #pragma unroll
    for (int i = 0; i < 4; ++i) bfr[i] = *(const bf16x8*)&B0[boff[i]];
    #pragma unroll
    for (int i = 0; i < 4; ++i) af[i]  = *(const bf16x8*)&A0[aoff[i]];
    if (st) stage_half(nb, 0, kt + 1);
    __builtin_amdgcn_s_barrier();
    __builtin_amdgcn_s_setprio(1);
    #pragma unroll
    for (int i = 0; i < 4; ++i)
      #pragma unroll
      for (int j = 0; j < 4; ++j)
        acc[i][j] = __builtin_amdgcn_mfma_f32_16x16x32_bf16(af[i], bfr[j], acc[i][j], 0, 0, 0);
    __builtin_amdgcn_s_setprio(0);
    __builtin_amdgcn_s_barrier();

    // ---- phase 2: kh0, M-half 1 (B reused); stage kt+1 kh1 ----
    #pragma unroll
    for (int i = 0; i < 4; ++i) af[i] = *(const bf16x8*)&A0[aoff[4 + i]];
    if (st) stage_half(nb, 1, kt + 1);
    __builtin_amdgcn_s_barrier();
    __builtin_amdgcn_s_setprio(1);
    #pragma unroll
    for (int i = 0; i < 4; ++i)
      #pragma unroll
      for (int j = 0; j < 4; ++j)
        acc[4 + i][j] = __builtin_amdgcn_mfma_f32_16x16x32_bf16(af[i], bfr[j], acc[4 + i][j], 0, 0, 0);
    __builtin_amdgcn_s_setprio(0);
    // counted wait: kh1(kt) landed; kt+1's 8 loads (if staged) keep flying
    if (st) { asm volatile("s_waitcnt vmcnt(8)" ::: "memory"); }
    else    { asm volatile("s_waitcnt vmcnt(0)" ::: "memory"); }
    __builtin_amdgcn_sched_barrier(0);
    __builtin_amdgcn_s_barrier();

    // ---- phase 3: kh1, M-half 0 ----
    #pragma unroll
    for (int i = 0; i < 4; ++i) bfr[i] = *(const bf16x8*)&B1[boff[i]];
    #pragma unroll
    for (int i = 0; i < 4; ++i) af[i]  = *(const bf16x8*)&A1[aoff[i]];
    __builtin_amdgcn_s_barrier();
    __builtin_amdgcn_s_setprio(1);
    #pragma unroll
    for (int i = 0; i < 4; ++i)
      #pragma unroll
      for (int j = 0; j < 4; ++j)
        acc[i][j] = __builtin_amdgcn_mfma_f32_16x16x32_bf16(af[i], bfr[j], acc[i][j], 0, 0, 0);
    __builtin_amdgcn_s_setprio(0);
    __builtin_amdgcn_s_barrier();

    // ---- phase 4: kh1, M-half 1 ----
    #pragma unroll
    for (int i = 0; i < 4; ++i) af[i] = *(const bf16x8*)&A1[aoff[4 + i]];
    __builtin_amdgcn_s_barrier();
    __builtin_amdgcn_s_setprio(1);
    #pragma unroll
    for (int i = 0; i < 4; ++i)
      #pragma unroll
      for (int j = 0; j < 4; ++j)
        acc[4 + i][j] = __builtin_amdgcn_mfma_f32_16x16x32_bf16(af[i], bfr[j], acc[4 + i][j], 0, 0, 0);
    __builtin_amdgcn_s_setprio(0);
    // counted end-of-iteration wait: kh0(kt+1) landed; kh1(kt+1) keeps flying
    if (st) { asm volatile("s_waitcnt vmcnt(4)" ::: "memory"); }
    __builtin_amdgcn_sched_barrier(0);
    __builtin_amdgcn_s_barrier();
  }

  #pragma unroll
  for (int mf = 0; mf < 8; ++mf)
    #pragma unroll
    for (int nf = 0; nf < 4; ++nf)
      #pragma unroll
      for (int g = 0; g < 4; ++g) {
        int r = row0 + wr * 128 + mf * 16 + lk * 4 + g;
        int c = col0 + wc * 64 + nf * 16 + lr;
        float v = acc[mf][nf][g];
        if (EPI == 5) {
          int seg = c >> 10;
          int cc = c & (BDIM - 1);
          void* dst = seg == 0 ? Cv : (seg == 1 ? Cv2 : (seg == 2 ? Cv3 : Cv4));
          if (seg < 2) {
            float xv = v + bias[cc];
            v = 0.5f * xv * (1.0f + erff(xv * 0.70710678118654752f));
          }
          ((__hip_bfloat16*)dst)[(size_t)r * BDIM + cc] = __float2bfloat16(v);
        } else {
          void* dst = Cv;
          int cc = c, ld = ldc;
          if (c >= csplit) { dst = Cv2; cc = c - csplit; ld = ldc2; }
          size_t idx = (size_t)r * ld + cc;
          if (EPI == 2) {
            float xv = v + bias[cc];
            float gl = 0.5f * xv * (1.0f + erff(xv * 0.70710678118654752f));
            ((__hip_bfloat16*)dst)[idx] = __float2bfloat16(gl);
          } else {  // EPI == 4: divide by n_valid, f32 out
            float s = 1.0f / (float)((r & (TDIM - 1)) + 1);
            ((float*)dst)[idx] = v * s;
          }
        }
      }
}

// ---------------- dual router (vectorized bf16x8 loads) ----------------
__global__ __launch_bounds__(256) void router_kernel(const __hip_bfloat16* __restrict__ Hf,
    const __hip_bfloat16* __restrict__ Hi,
    const float* __restrict__ w2, const float* __restrict__ b2,
    const float* __restrict__ ebias, float* __restrict__ wgt_f, float* __restrict__ wgt_i) {
  const __hip_bfloat16* H = blockIdx.y ? Hi : Hf;
  float* wgt = blockIdx.y ? wgt_i : wgt_f;
  int wv = threadIdx.x >> 6;
  int l  = threadIdx.x & 63;
  int row = blockIdx.x * 4 + wv;
  if (row >= BT) return;
  const short* Hs = (const short*)H;
  float acc[KEXPN] = {};
  #pragma unroll
  for (int i = 0; i < BDIM / 512; i++) {
    int h = (i * 64 + l) * 8;
    bf16x8 hv = *(const bf16x8*)(Hs + (size_t)row * BDIM + h);
    #pragma unroll
    for (int j = 0; j < 8; j++) {
      unsigned int ui = ((unsigned int)(unsigned short)hv[j]) << 16;
      float xv = __uint_as_float(ui);
      #pragma unroll
      for (int k = 0; k < KEXPN; k++) acc[k] += xv * w2[k * BDIM + h + j];
    }
  }
  #pragma unroll
  for (int k = 0; k < KEXPN; k++)
    for (int off = 32; off; off >>= 1) acc[k] += __shfl_down(acc[k], off);
  if (l == 0) {
    float lg[KEXPN];
    float mx = -1e30f;
    #pragma unroll
    for (int k = 0; k < KEXPN; k++) { lg[k] = acc[k] + b2[k] + ebias[k]; mx = fmaxf(mx, lg[k]); }
    float s = 0.0f;
    #pragma unroll
    for (int k = 0; k < KEXPN; k++) { lg[k] = expf(lg[k] - mx); s += lg[k]; }
    float inv = 1.0f / s;
    #pragma unroll
    for (int k = 0; k < KEXPN; k++) wgt[(size_t)row * KEXPN + k] = lg[k] * inv;
  }
}

// ---------------- cumsum phase 1: per-chunk sums (yW is bf16) ----------------
__global__ __launch_bounds__(1024) void chunksum_kernel(const __hip_bfloat16* __restrict__ yW,
    float* __restrict__ S) {
  int j  = threadIdx.x;
  int ch = blockIdx.x;
  int b  = blockIdx.y;
  size_t base = ((size_t)b * TDIM + ch * TC) * KRC + j;
  float s = 0.0f;
  for (int t = 0; t < TC; t++) s += __bfloat162float(yW[base + (size_t)t * KRC]);
  S[((size_t)b * NCH + ch) * KRC + j] = s;
}

// ---------------- cumsum phase 2: exclusive scan of chunk sums (in place) ----------------
__global__ __launch_bounds__(1024) void scan_chunks_kernel(float* __restrict__ S) {
  int j = threadIdx.x;
  int b = blockIdx.x;
  float run = 0.0f;
  for (int ch = 0; ch < NCH; ch++) {
    size_t i = ((size_t)b * NCH + ch) * KRC + j;
    float v = S[i];
    S[i] = run;
    run += v;
  }
}

// ---------------- cumsum phase 3 + combine both branches -> Pcat (+ ext cols fused) ----------------
__global__ __launch_bounds__(1024) void combine_kernel(const __hip_bfloat16* __restrict__ yW,
    const float* __restrict__ S, const __hip_bfloat16* __restrict__ xV,
    const float* __restrict__ wf, const float* __restrict__ wi,
    const float* __restrict__ alphaPtr, __hip_bfloat16* __restrict__ P) {
  int j  = threadIdx.x;
  int ch = blockIdx.x;
  int b  = blockIdx.y;
  float alpha = alphaPtr[0];
  float scale = (j < KR) ? 1.0f : alpha;
  const float* wgt = (j < KR) ? wf : wi;
  int k = (j & (KR - 1)) >> 6;
  float run = S[((size_t)b * NCH + ch) * KRC + j];
  for (int t0 = 0; t0 < TC; t0++) {
    size_t row = (size_t)b * TDIM + ch * TC + t0;
    run += __bfloat162float(yW[row * KRC + j]);
    float p = __bfloat162float(xV[row * KRC + j]) * run * wgt[row * KEXPN + k] * scale;
    P[row * PW2 + j] = __float2bfloat16(p);
  }
  if (j < 128) {
    int col = KRC + j;
    for (int t0 = 0; t0 < TC; t0++) {
      size_t row = (size_t)b * TDIM + ch * TC + t0;
      float v = 0.0f;
      if (j < KEXPN)          v = wf[row * KEXPN + j];
      else if (j < 2 * KEXPN) v = wi[row * KEXPN + (j - KEXPN)] * alpha;
      P[row * PW2 + col] = __float2bfloat16(v);
    }
  }
}

// ---------------- sentinel ----------------
__global__ __launch_bounds__(256) void fill_kernel(float* __restrict__ out, long n, float val) {
  long id = (long)blockIdx.x * 256 + threadIdx.x;
  if (id < n) out[id] = val;
}

extern "C" void kernel_launch(void* const* d_in, const int* in_sizes, int n_in,
                              void* d_out, int out_size, void* d_ws, size_t ws_size,
                              hipStream_t stream) {
  const float* x        = (const float*)d_in[0];
  const float* W_Q      = (const float*)d_in[1];
  const float* W_K      = (const float*)d_in[2];
  const float* W_O      = (const float*)d_in[3];
  const float* W_inv    = (const float*)d_in[4];
  const float* V_fwd    = (const float*)d_in[5];
  const float* W_fwd    = (const float*)d_in[6];
  const float* U_fwd    = (const float*)d_in[7];
  const float* b_fwd    = (const float*)d_in[8];
  const float* V_inv    = (const float*)d_in[9];
  const float* W_inv_e  = (const float*)d_in[10];
  const float* U_inv    = (const float*)d_in[11];
  const float* b_inv    = (const float*)d_in[12];
  const float* rw1      = (const float*)d_in[13];
  const float* rb1      = (const float*)d_in[14];
  const float* rw2      = (const float*)d_in[15];
  const float* rb2      = (const float*)d_in[16];
  const float* alphaPtr = (const float*)d_in[17];
  const float* ebias    = (const float*)d_in[18];

  char* ws = (char*)d_ws;
  size_t off = 0;
  auto alloc = [&](size_t sz) -> void* {
    void* p = ws + off;
    off += (sz + 255) & ~(size_t)255;
    return p;
  };

  const size_t RB = (size_t)BDIM * 2;
  void* winvT = alloc((size_t)BDIM * RB);
  void* wqT   = alloc((size_t)BDIM * RB);
  void* wkT   = alloc((size_t)BDIM * RB);
  void* wo    = alloc((size_t)BDIM * RB);
  void* ST    = alloc((size_t)2048 * RB);
  void* HXQ   = alloc((size_t)3072 * RB);
  void* XKA   = alloc((size_t)1024 * RB);
  void* BigB  = alloc((size_t)4096 * RB);
  void* UTT   = alloc((size_t)PW2 * RB);
  void* Mcat  = alloc((size_t)BDIM * PW2 * 2);
  void* wgt_f = alloc((size_t)BT * KEXPN * 4);
  void* wgt_i = alloc((size_t)BT * KEXPN * 4);
  void* S     = alloc((size_t)4 * NCH * KRC * 4);
  void* s_x   = alloc((size_t)BT * BDIM * 2);
  void* Hf    = alloc((size_t)BT * BDIM * 2);
  void* Hi    = alloc((size_t)BT * BDIM * 2);
  void* xVcat = alloc((size_t)BT * KRC * 2);
  void* yWcat = alloc((size_t)BT * KRC * 2);
  void* Pcat  = Hf;

  if (off > ws_size) {
    fill_kernel<<<dim3((unsigned)((out_size + 255) / 256)), 256, 0, stream>>>(
        (float*)d_out, (long)out_size, (float)(off >> 20));
    return;
  }

  __hip_bfloat16* STp  = (__hip_bfloat16*)ST;
  __hip_bfloat16* HXQp = (__hip_bfloat16*)HXQ;
  __hip_bfloat16* XKAp = (__hip_bfloat16*)XKA;
  __hip_bfloat16* BigBp= (__hip_bfloat16*)BigB;
  __hip_bfloat16* UTTp = (__hip_bfloat16*)UTT;

  auto cvt = [&](const float* in, void* out, long n) {
    long n4 = n / 4;
    cvt_bf16_kernel<<<dim3((unsigned)((n4 + 255) / 256)), dim3(256), 0, stream>>>(
        in, (__hip_bfloat16*)out, n4);
  };
  auto gemm2b = [&](const void* A, const void* Bm, void* C, void* C2, void* C3, void* C4,
                    int csplit, int ldc, int ldc2, int M, int N, int Kd, int epi,
                    const float* bias) {
    dim3 g(N / 256, M / 256);
    if (epi == 2)      gemm_nt_256<2><<<g, 512, 0, stream>>>((const __hip_bfloat16*)A, (const __hip_bfloat16*)Bm, C, C2, C3, C4, csplit, ldc, ldc2, bias, M, N, Kd);
    else if (epi == 5) gemm_nt_256<5><<<g, 512, 0, stream>>>((const __hip_bfloat16*)A, (const __hip_bfloat16*)Bm, C, C2, C3, C4, csplit, ldc, ldc2, bias, M, N, Kd);
    else               gemm_nt_256<4><<<g, 512, 0, stream>>>((const __hip_bfloat16*)A, (const __hip_bfloat16*)Bm, C, C2, C3, C4, csplit, ldc, ldc2, bias, M, N, Kd);
  };

  // ---- prep ----
  cvt(x,   s_x, (long)BT * BDIM);
  cvt(W_O, wo,  (long)BDIM * BDIM);
  cvt(rw1, STp,  (long)BDIM * BDIM);
  cvt(rw1, HXQp, (long)BDIM * BDIM);
  transpose3_kernel<<<dim3((BDIM * BDIM + 255) / 256, 3), 256, 0, stream>>>(
      W_inv, (__hip_bfloat16*)winvT, W_Q, (__hip_bfloat16*)wqT, W_K, (__hip_bfloat16*)wkT);
  vmat4_kernel<<<dim3((KR * BDIM + 255) / 256, 4), 256, 0, stream>>>(
      V_fwd,   HXQp + (size_t)2048 * BDIM,
      W_fwd,   XKAp,
      W_inv_e, STp + (size_t)1024 * BDIM,
      V_inv,   STp + (size_t)1536 * BDIM);
  utt_pack_kernel<<<dim3((PW2 * BDIM + 255) / 256), 256, 0, stream>>>(
      U_fwd, b_fwd, U_inv, b_inv, UTTp);

  // ---- folds: 2 launches, 2 parallel partitions each ----
  {
    FoldArgs f0 = { STp, (const __hip_bfloat16*)winvT,
                    HXQp + (size_t)1024 * BDIM, HXQp + (size_t)2560 * BDIM,
                    XKAp + (size_t)512 * BDIM, 1024, 1536, BDIM, 2048, BDIM, BDIM };
    FoldArgs f1 = { (const __hip_bfloat16*)wo, UTTp,
                    Mcat, nullptr, nullptr, 1 << 30, 1 << 30, PW2, BDIM, PW2, BDIM };
    int n0 = (f0.M / 128) * (f0.N / 128);
    int n1 = (f1.M / 128) * (f1.N / 128);
    gemm_fold2<<<dim3(n0 + n1), 256, 0, stream>>>(f0, f1, n0);
  }
  {
    FoldArgs f0 = { HXQp, (const __hip_bfloat16*)wqT,
                    BigBp, nullptr, nullptr, 1 << 30, 1 << 30, BDIM, 3072, BDIM, BDIM };
    FoldArgs f1 = { XKAp, (const __hip_bfloat16*)wkT,
                    BigBp + (size_t)3072 * BDIM, nullptr, nullptr, 1 << 30, 1 << 30,
                    BDIM, 1024, BDIM, BDIM };
    int n0 = (f0.M / 128) * (f0.N / 128);
    int n1 = (f1.M / 128) * (f1.N / 128);
    gemm_fold2<<<dim3(n0 + n1), 256, 0, stream>>>(f0, f1, n0);
  }

  // ---- ONE merged big GEMM: [Hf|Hi|xVcat|yWcat] = x @ BigB^T (N=4096, EPI=5) ----
  gemm2b(s_x, BigB, Hf, Hi, xVcat, yWcat, 0, 0, 0, BT, 4 * BDIM, BDIM, 5, rb1);

  // ---- dual router ----
  router_kernel<<<dim3(BT / 4, 2), 256, 0, stream>>>((const __hip_bfloat16*)Hf,
      (const __hip_bfloat16*)Hi, rw2, rb2, ebias, (float*)wgt_f, (float*)wgt_i);

  // ---- causal cumsum + combine into Pcat ----
  dim3 gch(NCH, 4);
  chunksum_kernel<<<gch, 1024, 0, stream>>>((const __hip_bfloat16*)yWcat, (float*)S);
  scan_chunks_kernel<<<dim3(4), 1024, 0, stream>>>((float*)S);
  combine_kernel<<<gch, 1024, 0, stream>>>((const __hip_bfloat16*)yWcat, (const float*)S,
      (const __hip_bfloat16*)xVcat, (const float*)wgt_f, (const float*)wgt_i,
      alphaPtr, (__hip_bfloat16*)Pcat);

  // ---- single output GEMM: out = diag(1/n) * Pcat @ Mcat^T (K=1152) ----
  gemm2b(Pcat, Mcat, d_out, d_out, nullptr, nullptr, BDIM, BDIM, BDIM,
         BT, BDIM, PW2, 4, nullptr);
}

// Round 15
// 457.830 us; speedup vs baseline: 1.0727x; 1.0727x over previous
//
#include <hip/hip_runtime.h>
#include <hip/hip_bf16.h>
#include <math.h>

#define BDIM 1024
#define TDIM 4096
#define BT   16384   // B*T
#define KEXPN 8
#define RRANK 64
#define KR   512     // KEXPN*RRANK
#define PW2  1152    // packed P width: 512 prod_f + 512 prod_i + 8 wf + 8 wi + 112 pad
#define KRC  1024    // concatenated xV/yW width
#define NCH  64
#define TC   64      // T per chunk (NCH*TC == TDIM)

typedef __attribute__((ext_vector_type(8))) short bf16x8;
typedef __attribute__((ext_vector_type(4))) float f32x4;

typedef __attribute__((address_space(1))) char g_char;
typedef __attribute__((address_space(3))) char l_char;

// async 16B global->LDS: per-lane global addr, wave-uniform LDS base (+lane*16 by HW)
__device__ __forceinline__ void gload16(const short* g, short* lds_base_uniform) {
  __builtin_amdgcn_global_load_lds((const g_char*)(const char*)g,
                                   (l_char*)(char*)lds_base_uniform, 16, 0, 0);
}

// ---------------- elementwise conversion f32 -> bf16 (vectorized x4) ----------------
__global__ __launch_bounds__(256) void cvt_bf16_kernel(const float* __restrict__ in,
    __hip_bfloat16* __restrict__ out, long n4) {
  long id = (long)blockIdx.x * 256 + threadIdx.x;
  if (id >= n4) return;
  f32x4 v = ((const f32x4*)in)[id];
  long i = id * 4;
  out[i + 0] = __float2bfloat16(v[0]);
  out[i + 1] = __float2bfloat16(v[1]);
  out[i + 2] = __float2bfloat16(v[2]);
  out[i + 3] = __float2bfloat16(v[3]);
}

// ---------------- merged transpose-pack x3: out[e][d] = in[d][e], D x D ----------------
__global__ __launch_bounds__(256) void transpose3_kernel(
    const float* __restrict__ in0, __hip_bfloat16* __restrict__ o0,
    const float* __restrict__ in1, __hip_bfloat16* __restrict__ o1,
    const float* __restrict__ in2, __hip_bfloat16* __restrict__ o2) {
  int id = blockIdx.x * 256 + threadIdx.x;
  if (id >= BDIM * BDIM) return;
  const float* in = blockIdx.y == 0 ? in0 : (blockIdx.y == 1 ? in1 : in2);
  __hip_bfloat16* out = blockIdx.y == 0 ? o0 : (blockIdx.y == 1 ? o1 : o2);
  int d = id & (BDIM - 1);
  int e = id >> 10;
  out[(size_t)e * BDIM + d] = __float2bfloat16(in[(size_t)d * BDIM + e]);
}

// ---------------- merged pack V x4: (K,D,R) -> [(k*64+r)][d] bf16 ----------------
__global__ __launch_bounds__(256) void vmat4_kernel(
    const float* __restrict__ i0, __hip_bfloat16* __restrict__ o0,
    const float* __restrict__ i1, __hip_bfloat16* __restrict__ o1,
    const float* __restrict__ i2, __hip_bfloat16* __restrict__ o2,
    const float* __restrict__ i3, __hip_bfloat16* __restrict__ o3) {
  int id = blockIdx.x * 256 + threadIdx.x;
  if (id >= KR * BDIM) return;
  const float* V = blockIdx.y == 0 ? i0 : (blockIdx.y == 1 ? i1 : (blockIdx.y == 2 ? i2 : i3));
  __hip_bfloat16* out = blockIdx.y == 0 ? o0 : (blockIdx.y == 1 ? o1 : (blockIdx.y == 2 ? o2 : o3));
  int d = id & (BDIM - 1);
  int kr = id >> 10;
  int k = kr >> 6, r = kr & 63;
  out[(size_t)kr * BDIM + d] = __float2bfloat16(V[((size_t)k * BDIM + d) * RRANK + r]);
}

// ---------------- pack UTT[c][e], c in [0,1152): Uf-prod | Ui-prod | bf | bi | zeros ----------------
__global__ __launch_bounds__(256) void utt_pack_kernel(
    const float* __restrict__ Uf, const float* __restrict__ bf,
    const float* __restrict__ Ui, const float* __restrict__ bi,
    __hip_bfloat16* __restrict__ out) {
  int id = blockIdx.x * 256 + threadIdx.x;
  if (id >= PW2 * BDIM) return;
  int e = id & (BDIM - 1);
  int c = id >> 10;
  float v = 0.0f;
  if (c < KR) {
    int k = c >> 6, r = c & 63;
    v = Uf[((size_t)k * BDIM + e) * RRANK + r];
  } else if (c < 2 * KR) {
    int c2 = c - KR;
    int k = c2 >> 6, r = c2 & 63;
    v = Ui[((size_t)k * BDIM + e) * RRANK + r];
  } else if (c < 2 * KR + KEXPN) {
    v = bf[(size_t)(c - 2 * KR) * BDIM + e];
  } else if (c < 2 * KR + 2 * KEXPN) {
    v = bi[(size_t)(c - 2 * KR - KEXPN) * BDIM + e];
  }
  out[(size_t)c * BDIM + e] = __float2bfloat16(v);
}

// ================= 128^2 2-phase fold engine, TWO parallel partitions per launch =================
struct FoldArgs {
  const __hip_bfloat16* A; const __hip_bfloat16* B;
  void* C1; void* C2; void* C3;
  int rs1, rs2, ldc, M, N, Kd;
};

__device__ __forceinline__ void fold_body(const FoldArgs fa, int bx, int by,
                                          short* Als, short* Bls) {
  const short* As = (const short*)fa.A;
  const short* Bs = (const short*)fa.B;
  const int Kd = fa.Kd;
  const int t  = threadIdx.x;
  const int w  = t >> 6;
  const int l  = t & 63;
  const int lr = l & 15;
  const int lk = l >> 4;
  const int wr = w >> 1;
  const int wc = w & 1;
  const int row0 = by * 128;
  const int col0 = bx * 128;
  const int srow = w * 16 + (l >> 2);
  const int scol = (l & 3) * 8;
  const short* ag0 = As + (size_t)(row0 + srow) * Kd + scol;
  const short* ag1 = As + (size_t)(row0 + 64 + srow) * Kd + scol;
  const short* bg0 = Bs + (size_t)(col0 + srow) * Kd + scol;
  const short* bg1 = Bs + (size_t)(col0 + 64 + srow) * Kd + scol;
  f32x4 acc[4][4] = {};
  const int nt = Kd / 32;
  auto stage = [&](int kt, int buf) {
    int k0 = kt * 32;
    gload16(ag0 + k0, Als + buf * 4096 + w * 512);
    gload16(ag1 + k0, Als + buf * 4096 + 2048 + w * 512);
    gload16(bg0 + k0, Bls + buf * 4096 + w * 512);
    gload16(bg1 + k0, Bls + buf * 4096 + 2048 + w * 512);
  };
  stage(0, 0);
  __syncthreads();
  int cur = 0;
  for (int kt = 0; kt < nt; ++kt) {
    if (kt + 1 < nt) stage(kt + 1, cur ^ 1);
    bf16x8 af[4], bfr[4];
    #pragma unroll
    for (int i = 0; i < 4; i++)
      af[i] = *(const bf16x8*)&Als[cur * 4096 + (wr * 64 + i * 16 + lr) * 32 + lk * 8];
    #pragma unroll
    for (int j = 0; j < 4; j++)
      bfr[j] = *(const bf16x8*)&Bls[cur * 4096 + (wc * 64 + j * 16 + lr) * 32 + lk * 8];
    #pragma unroll
    for (int i = 0; i < 4; i++)
      #pragma unroll
      for (int j = 0; j < 4; j++)
        acc[i][j] = __builtin_amdgcn_mfma_f32_16x16x32_bf16(af[i], bfr[j], acc[i][j], 0, 0, 0);
    __syncthreads();
    cur ^= 1;
  }
  #pragma unroll
  for (int i = 0; i < 4; i++)
    #pragma unroll
    for (int j = 0; j < 4; j++)
      #pragma unroll
      for (int g = 0; g < 4; g++) {
        int r = row0 + wr * 64 + i * 16 + lk * 4 + g;
        int c = col0 + wc * 64 + j * 16 + lr;
        void* dst = fa.C1; int rr = r;
        if (r >= fa.rs2)      { dst = fa.C3; rr = r - fa.rs2; }
        else if (r >= fa.rs1) { dst = fa.C2; rr = r - fa.rs1; }
        ((__hip_bfloat16*)dst)[(size_t)rr * fa.ldc + c] = __float2bfloat16(acc[i][j][g]);
      }
}

__global__ __launch_bounds__(256) void gemm_fold2(FoldArgs fa0, FoldArgs fa1, int nblk0) {
  __shared__ __align__(16) short Als[2 * 128 * 32];
  __shared__ __align__(16) short Bls[2 * 128 * 32];
  int id = blockIdx.x;
  if (id < nblk0) {
    int nbx = fa0.N / 128;
    fold_body(fa0, id % nbx, id / nbx, Als, Bls);
  } else {
    int lid = id - nblk0;
    int nbx = fa1.N / 128;
    fold_body(fa1, lid % nbx, lid / nbx, Als, Bls);
  }
}

// ================= 256^2 4-phase BK=64 engine (big GEMMs) — R10/R13 schedule =================
// EPI: 2 = bias+GELU->bf16 (2-seg), 4 = /n_valid->f32, 5 = 4-seg merged (gelu|gelu|bf16|bf16)
template<int EPI>
__global__ __launch_bounds__(512, 2) void gemm_nt_256(const __hip_bfloat16* __restrict__ A,
    const __hip_bfloat16* __restrict__ B, void* __restrict__ Cv, void* __restrict__ Cv2,
    void* __restrict__ Cv3, void* __restrict__ Cv4,
    int csplit, int ldc, int ldc2, const float* __restrict__ bias, int M, int N, int Kd) {
  __shared__ __align__(16) short Als[2][2][256 * 32];   // [buf][kh] 64 KB
  __shared__ __align__(16) short Bls[2][2][256 * 32];   // 64 KB

  int nbx = gridDim.x;
  int nwg = nbx * gridDim.y;
  int bx = blockIdx.x, by = blockIdx.y;
  if ((nwg & 7) == 0) {
    int orig = by * nbx + bx;
    int cpx = nwg >> 3;
    int id = (orig & 7) * cpx + (orig >> 3);
    bx = id % nbx; by = id / nbx;
  }
  const short* As = (const short*)A;
  const short* Bs = (const short*)B;
  const int t  = threadIdx.x;      // 0..511
  const int w  = t >> 6;           // 0..7
  const int l  = t & 63;
  const int lr = l & 15;
  const int lk = l >> 4;
  const int wr = w >> 2;           // 0..1 (M half)
  const int wc = w & 3;            // 0..3 (N quarter)
  const int row0 = by * 256;
  const int col0 = bx * 256;

  const int srow  = t >> 2;                       // 0..127
  const int sslot = (t & 3) ^ ((srow >> 1) & 3);
  const short* agA0 = As + (size_t)(row0 + srow) * Kd + sslot * 8;
  const short* agA1 = As + (size_t)(row0 + 128 + srow) * Kd + sslot * 8;
  const short* bgB0 = Bs + (size_t)(col0 + srow) * Kd + sslot * 8;
  const short* bgB1 = Bs + (size_t)(col0 + 128 + srow) * Kd + sslot * 8;

  auto stageA = [&](int buf, int kh, int kt) {
    int k0 = kt * 64 + kh * 32;
    short* base = &Als[buf][kh][0];
    gload16(agA0 + k0, base + w * 512);
    gload16(agA1 + k0, base + 4096 + w * 512);
  };
  auto stageB = [&](int buf, int kh, int kt) {
    int k0 = kt * 64 + kh * 32;
    short* base = &Bls[buf][kh][0];
    gload16(bgB0 + k0, base + w * 512);
    gload16(bgB1 + k0, base + 4096 + w * 512);
  };

  int aoff[8], boff[4];
  #pragma unroll
  for (int mf = 0; mf < 8; ++mf) {
    int r = wr * 128 + mf * 16 + lr;
    aoff[mf] = r * 32 + ((lk ^ ((r >> 1) & 3)) << 3);
  }
  #pragma unroll
  for (int nf = 0; nf < 4; ++nf) {
    int r = wc * 64 + nf * 16 + lr;
    boff[nf] = r * 32 + ((lk ^ ((r >> 1) & 3)) << 3);
  }

  f32x4 acc[8][4] = {};
  const int NT = Kd >> 6;   // K-tiles of 64

  stageA(0, 0, 0); stageA(0, 1, 0); stageB(0, 0, 0); stageB(0, 1, 0);
  asm volatile("s_waitcnt vmcnt(0)" ::: "memory");
  __builtin_amdgcn_sched_barrier(0);
  __builtin_amdgcn_s_barrier();

  for (int kt = 0; kt < NT; ++kt) {
    const int buf = kt & 1, nb = buf ^ 1;
    const short* A0 = &Als[buf][0][0];
    const short* A1 = &Als[buf][1][0];
    const short* B0 = &Bls[buf][0][0];
    const short* B1 = &Bls[buf][1][0];
    const bool st = (kt + 1 < NT);
    bf16x8 af[4], bfr[4];

    // ---- phase 1: kh0, M-half 0 ----
    #pragma unroll
    for (int i = 0; i < 4; ++i) bfr[i] = *(const bf16x8*)&B0[boff[i]];
    #pragma unroll
    for (int i = 0; i < 4; ++i) af[i]  = *(const bf16x8*)&A0[aoff[i]];
    if (st) { stageA(nb, 0, kt + 1); stageA(nb, 1, kt + 1); }
    __builtin_amdgcn_s_barrier();
    __builtin_amdgcn_s_setprio(1);
    #pragma unroll
    for (int i = 0; i < 4; ++i)
      #pragma unroll
      for (int j = 0; j < 4; ++j)
        acc[i][j] = __builtin_amdgcn_mfma_f32_16x16x32_bf16(af[i], bfr[j], acc[i][j], 0, 0, 0);
    __builtin_amdgcn_s_setprio(0);
    __builtin_amdgcn_s_barrier();

    // ---- phase 2: kh0, M-half 1 (B reused) ----
    #pragma unroll
    for (int i = 0; i < 4; ++i) af[i] = *(const bf16x8*)&A0[aoff[4 + i]];
    if (st) { stageB(nb, 0, kt + 1); stageB(nb, 1, kt + 1); }
    __builtin_amdgcn_s_barrier();
    __builtin_amdgcn_s_setprio(1);
    #pragma unroll
    for (int i = 0; i < 4; ++i)
      #pragma unroll
      for (int j = 0; j < 4; ++j)
        acc[4 + i][j] = __builtin_amdgcn_mfma_f32_16x16x32_bf16(af[i], bfr[j], acc[4 + i][j], 0, 0, 0);
    __builtin_amdgcn_s_setprio(0);
    __builtin_amdgcn_s_barrier();

    // ---- phase 3: kh1, M-half 0 ----
    #pragma unroll
    for (int i = 0; i < 4; ++i) bfr[i] = *(const bf16x8*)&B1[boff[i]];
    #pragma unroll
    for (int i = 0; i < 4; ++i) af[i]  = *(const bf16x8*)&A1[aoff[i]];
    __builtin_amdgcn_s_barrier();
    __builtin_amdgcn_s_setprio(1);
    #pragma unroll
    for (int i = 0; i < 4; ++i)
      #pragma unroll
      for (int j = 0; j < 4; ++j)
        acc[i][j] = __builtin_amdgcn_mfma_f32_16x16x32_bf16(af[i], bfr[j], acc[i][j], 0, 0, 0);
    __builtin_amdgcn_s_setprio(0);
    __builtin_amdgcn_s_barrier();

    // ---- phase 4: kh1, M-half 1 ----
    #pragma unroll
    for (int i = 0; i < 4; ++i) af[i] = *(const bf16x8*)&A1[aoff[4 + i]];
    __builtin_amdgcn_s_barrier();
    __builtin_amdgcn_s_setprio(1);
    #pragma unroll
    for (int i = 0; i < 4; ++i)
      #pragma unroll
      for (int j = 0; j < 4; ++j)
        acc[4 + i][j] = __builtin_amdgcn_mfma_f32_16x16x32_bf16(af[i], bfr[j], acc[4 + i][j], 0, 0, 0);
    __builtin_amdgcn_s_setprio(0);
    asm volatile("s_waitcnt vmcnt(0)" ::: "memory");
    __builtin_amdgcn_sched_barrier(0);
    __builtin_amdgcn_s_barrier();
  }

  #pragma unroll
  for (int mf = 0; mf < 8; ++mf)
    #pragma unroll
    for (int nf = 0; nf < 4; ++nf)
      #pragma unroll
      for (int g = 0; g < 4; ++g) {
        int r = row0 + wr * 128 + mf * 16 + lk * 4 + g;
        int c = col0 + wc * 64 + nf * 16 + lr;
        float v = acc[mf][nf][g];
        if (EPI == 5) {
          int seg = c >> 10;
          int cc = c & (BDIM - 1);
          void* dst = seg == 0 ? Cv : (seg == 1 ? Cv2 : (seg == 2 ? Cv3 : Cv4));
          if (seg < 2) {
            float xv = v + bias[cc];
            v = 0.5f * xv * (1.0f + erff(xv * 0.70710678118654752f));
          }
          ((__hip_bfloat16*)dst)[(size_t)r * BDIM + cc] = __float2bfloat16(v);
        } else {
          void* dst = Cv;
          int cc = c, ld = ldc;
          if (c >= csplit) { dst = Cv2; cc = c - csplit; ld = ldc2; }
          size_t idx = (size_t)r * ld + cc;
          if (EPI == 2) {
            float xv = v + bias[cc];
            float gl = 0.5f * xv * (1.0f + erff(xv * 0.70710678118654752f));
            ((__hip_bfloat16*)dst)[idx] = __float2bfloat16(gl);
          } else {  // EPI == 4: divide by n_valid, f32 out
            float s = 1.0f / (float)((r & (TDIM - 1)) + 1);
            ((float*)dst)[idx] = v * s;
          }
        }
      }
}

// ---------------- dual router (vectorized bf16x8 loads) ----------------
__global__ __launch_bounds__(256) void router_kernel(const __hip_bfloat16* __restrict__ Hf,
    const __hip_bfloat16* __restrict__ Hi,
    const float* __restrict__ w2, const float* __restrict__ b2,
    const float* __restrict__ ebias, float* __restrict__ wgt_f, float* __restrict__ wgt_i) {
  const __hip_bfloat16* H = blockIdx.y ? Hi : Hf;
  float* wgt = blockIdx.y ? wgt_i : wgt_f;
  int wv = threadIdx.x >> 6;
  int l  = threadIdx.x & 63;
  int row = blockIdx.x * 4 + wv;
  if (row >= BT) return;
  const short* Hs = (const short*)H;
  float acc[KEXPN] = {};
  #pragma unroll
  for (int i = 0; i < BDIM / 512; i++) {
    int h = (i * 64 + l) * 8;
    bf16x8 hv = *(const bf16x8*)(Hs + (size_t)row * BDIM + h);
    #pragma unroll
    for (int j = 0; j < 8; j++) {
      unsigned int ui = ((unsigned int)(unsigned short)hv[j]) << 16;
      float xv = __uint_as_float(ui);
      #pragma unroll
      for (int k = 0; k < KEXPN; k++) acc[k] += xv * w2[k * BDIM + h + j];
    }
  }
  #pragma unroll
  for (int k = 0; k < KEXPN; k++)
    for (int off = 32; off; off >>= 1) acc[k] += __shfl_down(acc[k], off);
  if (l == 0) {
    float lg[KEXPN];
    float mx = -1e30f;
    #pragma unroll
    for (int k = 0; k < KEXPN; k++) { lg[k] = acc[k] + b2[k] + ebias[k]; mx = fmaxf(mx, lg[k]); }
    float s = 0.0f;
    #pragma unroll
    for (int k = 0; k < KEXPN; k++) { lg[k] = expf(lg[k] - mx); s += lg[k]; }
    float inv = 1.0f / s;
    #pragma unroll
    for (int k = 0; k < KEXPN; k++) wgt[(size_t)row * KEXPN + k] = lg[k] * inv;
  }
}

// ---------------- cumsum phase 1: per-chunk sums (yW is bf16) ----------------
__global__ __launch_bounds__(1024) void chunksum_kernel(const __hip_bfloat16* __restrict__ yW,
    float* __restrict__ S) {
  int j  = threadIdx.x;
  int ch = blockIdx.x;
  int b  = blockIdx.y;
  size_t base = ((size_t)b * TDIM + ch * TC) * KRC + j;
  float s = 0.0f;
  for (int t = 0; t < TC; t++) s += __bfloat162float(yW[base + (size_t)t * KRC]);
  S[((size_t)b * NCH + ch) * KRC + j] = s;
}

// ---------------- cumsum phase 2: exclusive scan of chunk sums (in place) ----------------
__global__ __launch_bounds__(1024) void scan_chunks_kernel(float* __restrict__ S) {
  int j = threadIdx.x;
  int b = blockIdx.x;
  float run = 0.0f;
  for (int ch = 0; ch < NCH; ch++) {
    size_t i = ((size_t)b * NCH + ch) * KRC + j;
    float v = S[i];
    S[i] = run;
    run += v;
  }
}

// ---------------- cumsum phase 3 + combine both branches -> Pcat (+ ext cols fused) ----------------
__global__ __launch_bounds__(1024) void combine_kernel(const __hip_bfloat16* __restrict__ yW,
    const float* __restrict__ S, const __hip_bfloat16* __restrict__ xV,
    const float* __restrict__ wf, const float* __restrict__ wi,
    const float* __restrict__ alphaPtr, __hip_bfloat16* __restrict__ P) {
  int j  = threadIdx.x;
  int ch = blockIdx.x;
  int b  = blockIdx.y;
  float alpha = alphaPtr[0];
  float scale = (j < KR) ? 1.0f : alpha;
  const float* wgt = (j < KR) ? wf : wi;
  int k = (j & (KR - 1)) >> 6;
  float run = S[((size_t)b * NCH + ch) * KRC + j];
  for (int t0 = 0; t0 < TC; t0++) {
    size_t row = (size_t)b * TDIM + ch * TC + t0;
    run += __bfloat162float(yW[row * KRC + j]);
    float p = __bfloat162float(xV[row * KRC + j]) * run * wgt[row * KEXPN + k] * scale;
    P[row * PW2 + j] = __float2bfloat16(p);
  }
  if (j < 128) {
    int col = KRC + j;
    for (int t0 = 0; t0 < TC; t0++) {
      size_t row = (size_t)b * TDIM + ch * TC + t0;
      float v = 0.0f;
      if (j < KEXPN)          v = wf[row * KEXPN + j];
      else if (j < 2 * KEXPN) v = wi[row * KEXPN + (j - KEXPN)] * alpha;
      P[row * PW2 + col] = __float2bfloat16(v);
    }
  }
}

// ---------------- sentinel ----------------
__global__ __launch_bounds__(256) void fill_kernel(float* __restrict__ out, long n, float val) {
  long id = (long)blockIdx.x * 256 + threadIdx.x;
  if (id < n) out[id] = val;
}

extern "C" void kernel_launch(void* const* d_in, const int* in_sizes, int n_in,
                              void* d_out, int out_size, void* d_ws, size_t ws_size,
                              hipStream_t stream) {
  const float* x        = (const float*)d_in[0];
  const float* W_Q      = (const float*)d_in[1];
  const float* W_K      = (const float*)d_in[2];
  const float* W_O      = (const float*)d_in[3];
  const float* W_inv    = (const float*)d_in[4];
  const float* V_fwd    = (const float*)d_in[5];
  const float* W_fwd    = (const float*)d_in[6];
  const float* U_fwd    = (const float*)d_in[7];
  const float* b_fwd    = (const float*)d_in[8];
  const float* V_inv    = (const float*)d_in[9];
  const float* W_inv_e  = (const float*)d_in[10];
  const float* U_inv    = (const float*)d_in[11];
  const float* b_inv    = (const float*)d_in[12];
  const float* rw1      = (const float*)d_in[13];
  const float* rb1      = (const float*)d_in[14];
  const float* rw2      = (const float*)d_in[15];
  const float* rb2      = (const float*)d_in[16];
  const float* alphaPtr = (const float*)d_in[17];
  const float* ebias    = (const float*)d_in[18];

  char* ws = (char*)d_ws;
  size_t off = 0;
  auto alloc = [&](size_t sz) -> void* {
    void* p = ws + off;
    off += (sz + 255) & ~(size_t)255;
    return p;
  };

  const size_t RB = (size_t)BDIM * 2;
  void* winvT = alloc((size_t)BDIM * RB);
  void* wqT   = alloc((size_t)BDIM * RB);
  void* wkT   = alloc((size_t)BDIM * RB);
  void* wo    = alloc((size_t)BDIM * RB);
  void* ST    = alloc((size_t)2048 * RB);
  void* HXQ   = alloc((size_t)3072 * RB);
  void* XKA   = alloc((size_t)1024 * RB);
  void* BigB  = alloc((size_t)4096 * RB);
  void* UTT   = alloc((size_t)PW2 * RB);
  void* Mcat  = alloc((size_t)BDIM * PW2 * 2);
  void* wgt_f = alloc((size_t)BT * KEXPN * 4);
  void* wgt_i = alloc((size_t)BT * KEXPN * 4);
  void* S     = alloc((size_t)4 * NCH * KRC * 4);
  void* s_x   = alloc((size_t)BT * BDIM * 2);
  void* Hf    = alloc((size_t)BT * BDIM * 2);
  void* Hi    = alloc((size_t)BT * BDIM * 2);
  void* xVcat = alloc((size_t)BT * KRC * 2);
  void* yWcat = alloc((size_t)BT * KRC * 2);
  void* Pcat  = Hf;

  if (off > ws_size) {
    fill_kernel<<<dim3((unsigned)((out_size + 255) / 256)), 256, 0, stream>>>(
        (float*)d_out, (long)out_size, (float)(off >> 20));
    return;
  }

  __hip_bfloat16* STp  = (__hip_bfloat16*)ST;
  __hip_bfloat16* HXQp = (__hip_bfloat16*)HXQ;
  __hip_bfloat16* XKAp = (__hip_bfloat16*)XKA;
  __hip_bfloat16* BigBp= (__hip_bfloat16*)BigB;
  __hip_bfloat16* UTTp = (__hip_bfloat16*)UTT;

  auto cvt = [&](const float* in, void* out, long n) {
    long n4 = n / 4;
    cvt_bf16_kernel<<<dim3((unsigned)((n4 + 255) / 256)), dim3(256), 0, stream>>>(
        in, (__hip_bfloat16*)out, n4);
  };
  auto gemm2b = [&](const void* A, const void* Bm, void* C, void* C2, void* C3, void* C4,
                    int csplit, int ldc, int ldc2, int M, int N, int Kd, int epi,
                    const float* bias) {
    dim3 g(N / 256, M / 256);
    if (epi == 2)      gemm_nt_256<2><<<g, 512, 0, stream>>>((const __hip_bfloat16*)A, (const __hip_bfloat16*)Bm, C, C2, C3, C4, csplit, ldc, ldc2, bias, M, N, Kd);
    else if (epi == 5) gemm_nt_256<5><<<g, 512, 0, stream>>>((const __hip_bfloat16*)A, (const __hip_bfloat16*)Bm, C, C2, C3, C4, csplit, ldc, ldc2, bias, M, N, Kd);
    else               gemm_nt_256<4><<<g, 512, 0, stream>>>((const __hip_bfloat16*)A, (const __hip_bfloat16*)Bm, C, C2, C3, C4, csplit, ldc, ldc2, bias, M, N, Kd);
  };

  // ---- prep (7 launches) ----
  cvt(x,   s_x, (long)BT * BDIM);
  cvt(W_O, wo,  (long)BDIM * BDIM);
  cvt(rw1, STp,  (long)BDIM * BDIM);
  cvt(rw1, HXQp, (long)BDIM * BDIM);
  transpose3_kernel<<<dim3((BDIM * BDIM + 255) / 256, 3), 256, 0, stream>>>(
      W_inv, (__hip_bfloat16*)winvT, W_Q, (__hip_bfloat16*)wqT, W_K, (__hip_bfloat16*)wkT);
  vmat4_kernel<<<dim3((KR * BDIM + 255) / 256, 4), 256, 0, stream>>>(
      V_fwd,   HXQp + (size_t)2048 * BDIM,
      W_fwd,   XKAp,
      W_inv_e, STp + (size_t)1024 * BDIM,
      V_inv,   STp + (size_t)1536 * BDIM);
  utt_pack_kernel<<<dim3((PW2 * BDIM + 255) / 256), 256, 0, stream>>>(
      U_fwd, b_fwd, U_inv, b_inv, UTTp);

  // ---- folds: 2 launches, 2 parallel partitions each ----
  {
    FoldArgs f0 = { STp, (const __hip_bfloat16*)winvT,
                    HXQp + (size_t)1024 * BDIM, HXQp + (size_t)2560 * BDIM,
                    XKAp + (size_t)512 * BDIM, 1024, 1536, BDIM, 2048, BDIM, BDIM };
    FoldArgs f1 = { (const __hip_bfloat16*)wo, UTTp,
                    Mcat, nullptr, nullptr, 1 << 30, 1 << 30, PW2, BDIM, PW2, BDIM };
    int n0 = (f0.M / 128) * (f0.N / 128);
    int n1 = (f1.M / 128) * (f1.N / 128);
    gemm_fold2<<<dim3(n0 + n1), 256, 0, stream>>>(f0, f1, n0);
  }
  {
    FoldArgs f0 = { HXQp, (const __hip_bfloat16*)wqT,
                    BigBp, nullptr, nullptr, 1 << 30, 1 << 30, BDIM, 3072, BDIM, BDIM };
    FoldArgs f1 = { XKAp, (const __hip_bfloat16*)wkT,
                    BigBp + (size_t)3072 * BDIM, nullptr, nullptr, 1 << 30, 1 << 30,
                    BDIM, 1024, BDIM, BDIM };
    int n0 = (f0.M / 128) * (f0.N / 128);
    int n1 = (f1.M / 128) * (f1.N / 128);
    gemm_fold2<<<dim3(n0 + n1), 256, 0, stream>>>(f0, f1, n0);
  }

  // ---- ONE merged big GEMM: [Hf|Hi|xVcat|yWcat] = x @ BigB^T (N=4096, EPI=5) ----
  gemm2b(s_x, BigB, Hf, Hi, xVcat, yWcat, 0, 0, 0, BT, 4 * BDIM, BDIM, 5, rb1);

  // ---- dual router ----
  router_kernel<<<dim3(BT / 4, 2), 256, 0, stream>>>((const __hip_bfloat16*)Hf,
      (const __hip_bfloat16*)Hi, rw2, rb2, ebias, (float*)wgt_f, (float*)wgt_i);

  // ---- causal cumsum + combine into Pcat ----
  dim3 gch(NCH, 4);
  chunksum_kernel<<<gch, 1024, 0, stream>>>((const __hip_bfloat16*)yWcat, (float*)S);
  scan_chunks_kernel<<<dim3(4), 1024, 0, stream>>>((float*)S);
  combine_kernel<<<gch, 1024, 0, stream>>>((const __hip_bfloat16*)yWcat, (const float*)S,
      (const __hip_bfloat16*)xVcat, (const float*)wgt_f, (const float*)wgt_i,
      alphaPtr, (__hip_bfloat16*)Pcat);

  // ---- single output GEMM: out = diag(1/n) * Pcat @ Mcat^T (K=1152) ----
  gemm2b(Pcat, Mcat, d_out, d_out, nullptr, nullptr, BDIM, BDIM, BDIM,
         BT, BDIM, PW2, 4, nullptr);
}

// Round 16
// 446.044 us; speedup vs baseline: 1.1010x; 1.0264x over previous
//
#include <hip/hip_runtime.h>
#include <hip/hip_bf16.h>
#include <math.h>

#define BDIM 1024
#define TDIM 4096
#define BT   16384   // B*T
#define KEXPN 8
#define RRANK 64
#define KR   512     // KEXPN*RRANK
#define PW2  1152    // packed P width: 512 prod_f + 512 prod_i + 8 wf + 8 wi + 112 pad
#define KRC  1024    // concatenated xV/yW width
#define NCH  64
#define TC   64      // T per chunk (NCH*TC == TDIM)

typedef __attribute__((ext_vector_type(8))) short bf16x8;
typedef __attribute__((ext_vector_type(4))) float f32x4;

typedef __attribute__((address_space(1))) char g_char;
typedef __attribute__((address_space(3))) char l_char;

// async 16B global->LDS: per-lane global addr, wave-uniform LDS base (+lane*16 by HW)
__device__ __forceinline__ void gload16(const short* g, short* lds_base_uniform) {
  __builtin_amdgcn_global_load_lds((const g_char*)(const char*)g,
                                   (l_char*)(char*)lds_base_uniform, 16, 0, 0);
}

// ---------------- prep helpers ----------------
__device__ __forceinline__ void cvt4_body(const float* __restrict__ in,
    __hip_bfloat16* __restrict__ out, int blk) {
  long id = (long)blk * 256 + threadIdx.x;
  f32x4 v = ((const f32x4*)in)[id];
  long i = id * 4;
  out[i + 0] = __float2bfloat16(v[0]);
  out[i + 1] = __float2bfloat16(v[1]);
  out[i + 2] = __float2bfloat16(v[2]);
  out[i + 3] = __float2bfloat16(v[3]);
}
__device__ __forceinline__ void transpose_body(const float* __restrict__ in,
    __hip_bfloat16* __restrict__ out, int blk) {
  int id = blk * 256 + threadIdx.x;
  int d = id & (BDIM - 1);
  int e = id >> 10;
  out[(size_t)e * BDIM + d] = __float2bfloat16(in[(size_t)d * BDIM + e]);
}
__device__ __forceinline__ void vmat_body(const float* __restrict__ V,
    __hip_bfloat16* __restrict__ out, int blk) {
  int id = blk * 256 + threadIdx.x;
  int d = id & (BDIM - 1);
  int kr = id >> 10;
  int k = kr >> 6, r = kr & 63;
  out[(size_t)kr * BDIM + d] = __float2bfloat16(V[((size_t)k * BDIM + d) * RRANK + r]);
}
__device__ __forceinline__ void utt_body(const float* __restrict__ Uf,
    const float* __restrict__ bf, const float* __restrict__ Ui,
    const float* __restrict__ bi, __hip_bfloat16* __restrict__ out, int blk) {
  int id = blk * 256 + threadIdx.x;
  if (id >= PW2 * BDIM) return;
  int e = id & (BDIM - 1);
  int c = id >> 10;
  float v = 0.0f;
  if (c < KR) {
    int k = c >> 6, r = c & 63;
    v = Uf[((size_t)k * BDIM + e) * RRANK + r];
  } else if (c < 2 * KR) {
    int c2 = c - KR;
    int k = c2 >> 6, r = c2 & 63;
    v = Ui[((size_t)k * BDIM + e) * RRANK + r];
  } else if (c < 2 * KR + KEXPN) {
    v = bf[(size_t)(c - 2 * KR) * BDIM + e];
  } else if (c < 2 * KR + 2 * KEXPN) {
    v = bi[(size_t)(c - 2 * KR - KEXPN) * BDIM + e];
  }
  out[(size_t)c * BDIM + e] = __float2bfloat16(v);
}

// ---------------- ONE merged prep kernel: 12 partitioned jobs ----------------
#define PB0 16384            // cvt x
#define PB1 (PB0 + 1024)     // cvt W_O
#define PB2 (PB1 + 1024)     // cvt rw1 -> ST
#define PB3 (PB2 + 1024)     // cvt rw1 -> HXQ
#define PB4 (PB3 + 4096)     // transpose W_inv
#define PB5 (PB4 + 4096)     // transpose W_Q
#define PB6 (PB5 + 4096)     // transpose W_K
#define PB7 (PB6 + 2048)     // vmat V_fwd
#define PB8 (PB7 + 2048)     // vmat W_fwd
#define PB9 (PB8 + 2048)     // vmat W_inv_e
#define PB10 (PB9 + 2048)    // vmat V_inv
#define PB11 (PB10 + 4608)   // utt_pack
__global__ __launch_bounds__(256) void mega_prep_kernel(
    const float* __restrict__ x,      __hip_bfloat16* __restrict__ s_x,
    const float* __restrict__ W_O,    __hip_bfloat16* __restrict__ wo,
    const float* __restrict__ rw1,    __hip_bfloat16* __restrict__ STp,
    __hip_bfloat16* __restrict__ HXQp,
    const float* __restrict__ W_inv,  __hip_bfloat16* __restrict__ winvT,
    const float* __restrict__ W_Q,    __hip_bfloat16* __restrict__ wqT,
    const float* __restrict__ W_K,    __hip_bfloat16* __restrict__ wkT,
    const float* __restrict__ V_fwd,  const float* __restrict__ W_fwd,
    const float* __restrict__ W_inv_e,const float* __restrict__ V_inv,
    __hip_bfloat16* __restrict__ XKAp,
    const float* __restrict__ U_fwd,  const float* __restrict__ b_fwd,
    const float* __restrict__ U_inv,  const float* __restrict__ b_inv,
    __hip_bfloat16* __restrict__ UTTp) {
  int b = blockIdx.x;
  if (b < PB0)       cvt4_body(x, s_x, b);
  else if (b < PB1)  cvt4_body(W_O, wo, b - PB0);
  else if (b < PB2)  cvt4_body(rw1, STp, b - PB1);
  else if (b < PB3)  cvt4_body(rw1, HXQp, b - PB2);
  else if (b < PB4)  transpose_body(W_inv, winvT, b - PB3);
  else if (b < PB5)  transpose_body(W_Q, wqT, b - PB4);
  else if (b < PB6)  transpose_body(W_K, wkT, b - PB5);
  else if (b < PB7)  vmat_body(V_fwd, HXQp + (size_t)2048 * BDIM, b - PB6);
  else if (b < PB8)  vmat_body(W_fwd, XKAp, b - PB7);
  else if (b < PB9)  vmat_body(W_inv_e, STp + (size_t)1024 * BDIM, b - PB8);
  else if (b < PB10) vmat_body(V_inv, STp + (size_t)1536 * BDIM, b - PB9);
  else               utt_body(U_fwd, b_fwd, U_inv, b_inv, UTTp, b - PB10);
}

// ================= 128^2 2-phase fold engine, TWO parallel partitions per launch =================
struct FoldArgs {
  const __hip_bfloat16* A; const __hip_bfloat16* B;
  void* C1; void* C2; void* C3;
  int rs1, rs2, ldc, M, N, Kd;
};

__device__ __forceinline__ void fold_body(const FoldArgs fa, int bx, int by,
                                          short* Als, short* Bls) {
  const short* As = (const short*)fa.A;
  const short* Bs = (const short*)fa.B;
  const int Kd = fa.Kd;
  const int t  = threadIdx.x;
  const int w  = t >> 6;
  const int l  = t & 63;
  const int lr = l & 15;
  const int lk = l >> 4;
  const int wr = w >> 1;
  const int wc = w & 1;
  const int row0 = by * 128;
  const int col0 = bx * 128;
  const int srow = w * 16 + (l >> 2);
  const int scol = (l & 3) * 8;
  const short* ag0 = As + (size_t)(row0 + srow) * Kd + scol;
  const short* ag1 = As + (size_t)(row0 + 64 + srow) * Kd + scol;
  const short* bg0 = Bs + (size_t)(col0 + srow) * Kd + scol;
  const short* bg1 = Bs + (size_t)(col0 + 64 + srow) * Kd + scol;
  f32x4 acc[4][4] = {};
  const int nt = Kd / 32;
  auto stage = [&](int kt, int buf) {
    int k0 = kt * 32;
    gload16(ag0 + k0, Als + buf * 4096 + w * 512);
    gload16(ag1 + k0, Als + buf * 4096 + 2048 + w * 512);
    gload16(bg0 + k0, Bls + buf * 4096 + w * 512);
    gload16(bg1 + k0, Bls + buf * 4096 + 2048 + w * 512);
  };
  stage(0, 0);
  __syncthreads();
  int cur = 0;
  for (int kt = 0; kt < nt; ++kt) {
    if (kt + 1 < nt) stage(kt + 1, cur ^ 1);
    bf16x8 af[4], bfr[4];
    #pragma unroll
    for (int i = 0; i < 4; i++)
      af[i] = *(const bf16x8*)&Als[cur * 4096 + (wr * 64 + i * 16 + lr) * 32 + lk * 8];
    #pragma unroll
    for (int j = 0; j < 4; j++)
      bfr[j] = *(const bf16x8*)&Bls[cur * 4096 + (wc * 64 + j * 16 + lr) * 32 + lk * 8];
    #pragma unroll
    for (int i = 0; i < 4; i++)
      #pragma unroll
      for (int j = 0; j < 4; j++)
        acc[i][j] = __builtin_amdgcn_mfma_f32_16x16x32_bf16(af[i], bfr[j], acc[i][j], 0, 0, 0);
    __syncthreads();
    cur ^= 1;
  }
  #pragma unroll
  for (int i = 0; i < 4; i++)
    #pragma unroll
    for (int j = 0; j < 4; j++)
      #pragma unroll
      for (int g = 0; g < 4; g++) {
        int r = row0 + wr * 64 + i * 16 + lk * 4 + g;
        int c = col0 + wc * 64 + j * 16 + lr;
        void* dst = fa.C1; int rr = r;
        if (r >= fa.rs2)      { dst = fa.C3; rr = r - fa.rs2; }
        else if (r >= fa.rs1) { dst = fa.C2; rr = r - fa.rs1; }
        ((__hip_bfloat16*)dst)[(size_t)rr * fa.ldc + c] = __float2bfloat16(acc[i][j][g]);
      }
}

__global__ __launch_bounds__(256) void gemm_fold2(FoldArgs fa0, FoldArgs fa1, int nblk0) {
  __shared__ __align__(16) short Als[2 * 128 * 32];
  __shared__ __align__(16) short Bls[2 * 128 * 32];
  int id = blockIdx.x;
  if (id < nblk0) {
    int nbx = fa0.N / 128;
    fold_body(fa0, id % nbx, id / nbx, Als, Bls);
  } else {
    int lid = id - nblk0;
    int nbx = fa1.N / 128;
    fold_body(fa1, lid % nbx, lid / nbx, Als, Bls);
  }
}

// ================= 256^2 4-phase BK=64 engine (big GEMMs) — R13 schedule =================
// EPI: 2 = bias+GELU->bf16 (2-seg), 4 = /n_valid->f32, 5 = 4-seg merged (gelu|gelu|bf16|bf16)
template<int EPI>
__global__ __launch_bounds__(512, 2) void gemm_nt_256(const __hip_bfloat16* __restrict__ A,
    const __hip_bfloat16* __restrict__ B, void* __restrict__ Cv, void* __restrict__ Cv2,
    void* __restrict__ Cv3, void* __restrict__ Cv4,
    int csplit, int ldc, int ldc2, const float* __restrict__ bias, int M, int N, int Kd) {
  __shared__ __align__(16) short Als[2][2][256 * 32];   // [buf][kh] 64 KB
  __shared__ __align__(16) short Bls[2][2][256 * 32];   // 64 KB

  int nbx = gridDim.x;
  int nwg = nbx * gridDim.y;
  int bx = blockIdx.x, by = blockIdx.y;
  if ((nwg & 7) == 0) {
    int orig = by * nbx + bx;
    int cpx = nwg >> 3;
    int id = (orig & 7) * cpx + (orig >> 3);
    bx = id % nbx; by = id / nbx;
  }
  const short* As = (const short*)A;
  const short* Bs = (const short*)B;
  const int t  = threadIdx.x;      // 0..511
  const int w  = t >> 6;           // 0..7
  const int l  = t & 63;
  const int lr = l & 15;
  const int lk = l >> 4;
  const int wr = w >> 2;           // 0..1 (M half)
  const int wc = w & 3;            // 0..3 (N quarter)
  const int row0 = by * 256;
  const int col0 = bx * 256;

  const int srow  = t >> 2;                       // 0..127
  const int sslot = (t & 3) ^ ((srow >> 1) & 3);
  const short* agA0 = As + (size_t)(row0 + srow) * Kd + sslot * 8;
  const short* agA1 = As + (size_t)(row0 + 128 + srow) * Kd + sslot * 8;
  const short* bgB0 = Bs + (size_t)(col0 + srow) * Kd + sslot * 8;
  const short* bgB1 = Bs + (size_t)(col0 + 128 + srow) * Kd + sslot * 8;

  auto stageA = [&](int buf, int kh, int kt) {
    int k0 = kt * 64 + kh * 32;
    short* base = &Als[buf][kh][0];
    gload16(agA0 + k0, base + w * 512);
    gload16(agA1 + k0, base + 4096 + w * 512);
  };
  auto stageB = [&](int buf, int kh, int kt) {
    int k0 = kt * 64 + kh * 32;
    short* base = &Bls[buf][kh][0];
    gload16(bgB0 + k0, base + w * 512);
    gload16(bgB1 + k0, base + 4096 + w * 512);
  };

  int aoff[8], boff[4];
  #pragma unroll
  for (int mf = 0; mf < 8; ++mf) {
    int r = wr * 128 + mf * 16 + lr;
    aoff[mf] = r * 32 + ((lk ^ ((r >> 1) & 3)) << 3);
  }
  #pragma unroll
  for (int nf = 0; nf < 4; ++nf) {
    int r = wc * 64 + nf * 16 + lr;
    boff[nf] = r * 32 + ((lk ^ ((r >> 1) & 3)) << 3);
  }

  f32x4 acc[8][4] = {};
  const int NT = Kd >> 6;   // K-tiles of 64

  stageA(0, 0, 0); stageA(0, 1, 0); stageB(0, 0, 0); stageB(0, 1, 0);
  asm volatile("s_waitcnt vmcnt(0)" ::: "memory");
  __builtin_amdgcn_sched_barrier(0);
  __builtin_amdgcn_s_barrier();

  for (int kt = 0; kt < NT; ++kt) {
    const int buf = kt & 1, nb = buf ^ 1;
    const short* A0 = &Als[buf][0][0];
    const short* A1 = &Als[buf][1][0];
    const short* B0 = &Bls[buf][0][0];
    const short* B1 = &Bls[buf][1][0];
    const bool st = (kt + 1 < NT);
    bf16x8 af[4], bfr[4];

    // ---- phase 1: kh0, M-half 0 ----
    #pragma unroll
    for (int i = 0; i < 4; ++i) bfr[i] = *(const bf16x8*)&B0[boff[i]];
    #pragma unroll
    for (int i = 0; i < 4; ++i) af[i]  = *(const bf16x8*)&A0[aoff[i]];
    if (st) { stageA(nb, 0, kt + 1); stageA(nb, 1, kt + 1); }
    __builtin_amdgcn_s_barrier();
    __builtin_amdgcn_s_setprio(1);
    #pragma unroll
    for (int i = 0; i < 4; ++i)
      #pragma unroll
      for (int j = 0; j < 4; ++j)
        acc[i][j] = __builtin_amdgcn_mfma_f32_16x16x32_bf16(af[i], bfr[j], acc[i][j], 0, 0, 0);
    __builtin_amdgcn_s_setprio(0);
    __builtin_amdgcn_s_barrier();

    // ---- phase 2: kh0, M-half 1 (B reused) ----
    #pragma unroll
    for (int i = 0; i < 4; ++i) af[i] = *(const bf16x8*)&A0[aoff[4 + i]];
    if (st) { stageB(nb, 0, kt + 1); stageB(nb, 1, kt + 1); }
    __builtin_amdgcn_s_barrier();
    __builtin_amdgcn_s_setprio(1);
    #pragma unroll
    for (int i = 0; i < 4; ++i)
      #pragma unroll
      for (int j = 0; j < 4; ++j)
        acc[4 + i][j] = __builtin_amdgcn_mfma_f32_16x16x32_bf16(af[i], bfr[j], acc[4 + i][j], 0, 0, 0);
    __builtin_amdgcn_s_setprio(0);
    __builtin_amdgcn_s_barrier();

    // ---- phase 3: kh1, M-half 0 ----
    #pragma unroll
    for (int i = 0; i < 4; ++i) bfr[i] = *(const bf16x8*)&B1[boff[i]];
    #pragma unroll
    for (int i = 0; i < 4; ++i) af[i]  = *(const bf16x8*)&A1[aoff[i]];
    __builtin_amdgcn_s_barrier();
    __builtin_amdgcn_s_setprio(1);
    #pragma unroll
    for (int i = 0; i < 4; ++i)
      #pragma unroll
      for (int j = 0; j < 4; ++j)
        acc[i][j] = __builtin_amdgcn_mfma_f32_16x16x32_bf16(af[i], bfr[j], acc[i][j], 0, 0, 0);
    __builtin_amdgcn_s_setprio(0);
    __builtin_amdgcn_s_barrier();

    // ---- phase 4: kh1, M-half 1 ----
    #pragma unroll
    for (int i = 0; i < 4; ++i) af[i] = *(const bf16x8*)&A1[aoff[4 + i]];
    __builtin_amdgcn_s_barrier();
    __builtin_amdgcn_s_setprio(1);
    #pragma unroll
    for (int i = 0; i < 4; ++i)
      #pragma unroll
      for (int j = 0; j < 4; ++j)
        acc[4 + i][j] = __builtin_amdgcn_mfma_f32_16x16x32_bf16(af[i], bfr[j], acc[4 + i][j], 0, 0, 0);
    __builtin_amdgcn_s_setprio(0);
    asm volatile("s_waitcnt vmcnt(0)" ::: "memory");
    __builtin_amdgcn_sched_barrier(0);
    __builtin_amdgcn_s_barrier();
  }

  #pragma unroll
  for (int mf = 0; mf < 8; ++mf)
    #pragma unroll
    for (int nf = 0; nf < 4; ++nf)
      #pragma unroll
      for (int g = 0; g < 4; ++g) {
        int r = row0 + wr * 128 + mf * 16 + lk * 4 + g;
        int c = col0 + wc * 64 + nf * 16 + lr;
        float v = acc[mf][nf][g];
        if (EPI == 5) {
          int seg = c >> 10;
          int cc = c & (BDIM - 1);
          void* dst = seg == 0 ? Cv : (seg == 1 ? Cv2 : (seg == 2 ? Cv3 : Cv4));
          if (seg < 2) {
            float xv = v + bias[cc];
            v = 0.5f * xv * (1.0f + erff(xv * 0.70710678118654752f));
          }
          ((__hip_bfloat16*)dst)[(size_t)r * BDIM + cc] = __float2bfloat16(v);
        } else {
          void* dst = Cv;
          int cc = c, ld = ldc;
          if (c >= csplit) { dst = Cv2; cc = c - csplit; ld = ldc2; }
          size_t idx = (size_t)r * ld + cc;
          if (EPI == 2) {
            float xv = v + bias[cc];
            float gl = 0.5f * xv * (1.0f + erff(xv * 0.70710678118654752f));
            ((__hip_bfloat16*)dst)[idx] = __float2bfloat16(gl);
          } else {  // EPI == 4: divide by n_valid, f32 out
            float s = 1.0f / (float)((r & (TDIM - 1)) + 1);
            ((float*)dst)[idx] = v * s;
          }
        }
      }
}

// ---------------- merged router + chunksum (both consume the big GEMM only) ----------------
// blocks [0, 8192): router (branch = blk>>12, 4 rows per block, 256 thr)
// blocks [8192, 9216): chunksum (1024 blocks x 256 thr; per-column serial sum unchanged)
__global__ __launch_bounds__(256) void router_chunksum_kernel(
    const __hip_bfloat16* __restrict__ Hf, const __hip_bfloat16* __restrict__ Hi,
    const float* __restrict__ w2, const float* __restrict__ b2,
    const float* __restrict__ ebias, float* __restrict__ wgt_f, float* __restrict__ wgt_i,
    const __hip_bfloat16* __restrict__ yW, float* __restrict__ S) {
  int blk = blockIdx.x;
  if (blk < 8192) {
    const __hip_bfloat16* H = (blk >> 12) ? Hi : Hf;
    float* wgt = (blk >> 12) ? wgt_i : wgt_f;
    int rowblk = blk & 4095;
    int wv = threadIdx.x >> 6;
    int l  = threadIdx.x & 63;
    int row = rowblk * 4 + wv;
    const short* Hs = (const short*)H;
    float acc[KEXPN] = {};
    #pragma unroll
    for (int i = 0; i < BDIM / 512; i++) {
      int h = (i * 64 + l) * 8;
      bf16x8 hv = *(const bf16x8*)(Hs + (size_t)row * BDIM + h);
      #pragma unroll
      for (int j = 0; j < 8; j++) {
        unsigned int ui = ((unsigned int)(unsigned short)hv[j]) << 16;
        float xv = __uint_as_float(ui);
        #pragma unroll
        for (int k = 0; k < KEXPN; k++) acc[k] += xv * w2[k * BDIM + h + j];
      }
    }
    #pragma unroll
    for (int k = 0; k < KEXPN; k++)
      for (int off = 32; off; off >>= 1) acc[k] += __shfl_down(acc[k], off);
    if (l == 0) {
      float lg[KEXPN];
      float mx = -1e30f;
      #pragma unroll
      for (int k = 0; k < KEXPN; k++) { lg[k] = acc[k] + b2[k] + ebias[k]; mx = fmaxf(mx, lg[k]); }
      float s = 0.0f;
      #pragma unroll
      for (int k = 0; k < KEXPN; k++) { lg[k] = expf(lg[k] - mx); s += lg[k]; }
      float inv = 1.0f / s;
      #pragma unroll
      for (int k = 0; k < KEXPN; k++) wgt[(size_t)row * KEXPN + k] = lg[k] * inv;
    }
  } else {
    int cid = blk - 8192;          // 0..1023
    int b   = cid >> 8;            // 0..3
    int rem = cid & 255;
    int ch  = rem >> 2;            // 0..63
    int cg  = rem & 3;             // 0..3
    int j   = cg * 256 + threadIdx.x;
    size_t base = ((size_t)b * TDIM + ch * TC) * KRC + j;
    float s = 0.0f;
    for (int t = 0; t < TC; t++) s += __bfloat162float(yW[base + (size_t)t * KRC]);
    S[((size_t)b * NCH + ch) * KRC + j] = s;
  }
}

// ---------------- cumsum phase 2: exclusive scan of chunk sums (in place) ----------------
__global__ __launch_bounds__(1024) void scan_chunks_kernel(float* __restrict__ S) {
  int j = threadIdx.x;
  int b = blockIdx.x;
  float run = 0.0f;
  for (int ch = 0; ch < NCH; ch++) {
    size_t i = ((size_t)b * NCH + ch) * KRC + j;
    float v = S[i];
    S[i] = run;
    run += v;
  }
}

// ---------------- cumsum phase 3 + combine both branches -> Pcat (+ ext cols fused) ----------------
__global__ __launch_bounds__(1024) void combine_kernel(const __hip_bfloat16* __restrict__ yW,
    const float* __restrict__ S, const __hip_bfloat16* __restrict__ xV,
    const float* __restrict__ wf, const float* __restrict__ wi,
    const float* __restrict__ alphaPtr, __hip_bfloat16* __restrict__ P) {
  int j  = threadIdx.x;
  int ch = blockIdx.x;
  int b  = blockIdx.y;
  float alpha = alphaPtr[0];
  float scale = (j < KR) ? 1.0f : alpha;
  const float* wgt = (j < KR) ? wf : wi;
  int k = (j & (KR - 1)) >> 6;
  float run = S[((size_t)b * NCH + ch) * KRC + j];
  for (int t0 = 0; t0 < TC; t0++) {
    size_t row = (size_t)b * TDIM + ch * TC + t0;
    run += __bfloat162float(yW[row * KRC + j]);
    float p = __bfloat162float(xV[row * KRC + j]) * run * wgt[row * KEXPN + k] * scale;
    P[row * PW2 + j] = __float2bfloat16(p);
  }
  if (j < 128) {
    int col = KRC + j;
    for (int t0 = 0; t0 < TC; t0++) {
      size_t row = (size_t)b * TDIM + ch * TC + t0;
      float v = 0.0f;
      if (j < KEXPN)          v = wf[row * KEXPN + j];
      else if (j < 2 * KEXPN) v = wi[row * KEXPN + (j - KEXPN)] * alpha;
      P[row * PW2 + col] = __float2bfloat16(v);
    }
  }
}

// ---------------- sentinel ----------------
__global__ __launch_bounds__(256) void fill_kernel(float* __restrict__ out, long n, float val) {
  long id = (long)blockIdx.x * 256 + threadIdx.x;
  if (id < n) out[id] = val;
}

extern "C" void kernel_launch(void* const* d_in, const int* in_sizes, int n_in,
                              void* d_out, int out_size, void* d_ws, size_t ws_size,
                              hipStream_t stream) {
  const float* x        = (const float*)d_in[0];
  const float* W_Q      = (const float*)d_in[1];
  const float* W_K      = (const float*)d_in[2];
  const float* W_O      = (const float*)d_in[3];
  const float* W_inv    = (const float*)d_in[4];
  const float* V_fwd    = (const float*)d_in[5];
  const float* W_fwd    = (const float*)d_in[6];
  const float* U_fwd    = (const float*)d_in[7];
  const float* b_fwd    = (const float*)d_in[8];
  const float* V_inv    = (const float*)d_in[9];
  const float* W_inv_e  = (const float*)d_in[10];
  const float* U_inv    = (const float*)d_in[11];
  const float* b_inv    = (const float*)d_in[12];
  const float* rw1      = (const float*)d_in[13];
  const float* rb1      = (const float*)d_in[14];
  const float* rw2      = (const float*)d_in[15];
  const float* rb2      = (const float*)d_in[16];
  const float* alphaPtr = (const float*)d_in[17];
  const float* ebias    = (const float*)d_in[18];

  char* ws = (char*)d_ws;
  size_t off = 0;
  auto alloc = [&](size_t sz) -> void* {
    void* p = ws + off;
    off += (sz + 255) & ~(size_t)255;
    return p;
  };

  const size_t RB = (size_t)BDIM * 2;
  void* winvT = alloc((size_t)BDIM * RB);
  void* wqT   = alloc((size_t)BDIM * RB);
  void* wkT   = alloc((size_t)BDIM * RB);
  void* wo    = alloc((size_t)BDIM * RB);
  void* ST    = alloc((size_t)2048 * RB);
  void* HXQ   = alloc((size_t)3072 * RB);
  void* XKA   = alloc((size_t)1024 * RB);
  void* BigB  = alloc((size_t)4096 * RB);
  void* UTT   = alloc((size_t)PW2 * RB);
  void* Mcat  = alloc((size_t)BDIM * PW2 * 2);
  void* wgt_f = alloc((size_t)BT * KEXPN * 4);
  void* wgt_i = alloc((size_t)BT * KEXPN * 4);
  void* S     = alloc((size_t)4 * NCH * KRC * 4);
  void* s_x   = alloc((size_t)BT * BDIM * 2);
  void* Hf    = alloc((size_t)BT * BDIM * 2);
  void* Hi    = alloc((size_t)BT * BDIM * 2);
  void* xVcat = alloc((size_t)BT * KRC * 2);
  void* yWcat = alloc((size_t)BT * KRC * 2);
  void* Pcat  = Hf;

  if (off > ws_size) {
    fill_kernel<<<dim3((unsigned)((out_size + 255) / 256)), 256, 0, stream>>>(
        (float*)d_out, (long)out_size, (float)(off >> 20));
    return;
  }

  __hip_bfloat16* STp  = (__hip_bfloat16*)ST;
  __hip_bfloat16* HXQp = (__hip_bfloat16*)HXQ;
  __hip_bfloat16* XKAp = (__hip_bfloat16*)XKA;
  __hip_bfloat16* BigBp= (__hip_bfloat16*)BigB;
  __hip_bfloat16* UTTp = (__hip_bfloat16*)UTT;

  auto gemm2b = [&](const void* A, const void* Bm, void* C, void* C2, void* C3, void* C4,
                    int csplit, int ldc, int ldc2, int M, int N, int Kd, int epi,
                    const float* bias) {
    dim3 g(N / 256, M / 256);
    if (epi == 2)      gemm_nt_256<2><<<g, 512, 0, stream>>>((const __hip_bfloat16*)A, (const __hip_bfloat16*)Bm, C, C2, C3, C4, csplit, ldc, ldc2, bias, M, N, Kd);
    else if (epi == 5) gemm_nt_256<5><<<g, 512, 0, stream>>>((const __hip_bfloat16*)A, (const __hip_bfloat16*)Bm, C, C2, C3, C4, csplit, ldc, ldc2, bias, M, N, Kd);
    else               gemm_nt_256<4><<<g, 512, 0, stream>>>((const __hip_bfloat16*)A, (const __hip_bfloat16*)Bm, C, C2, C3, C4, csplit, ldc, ldc2, bias, M, N, Kd);
  };

  // ---- ONE merged prep launch (12 partitioned jobs) ----
  mega_prep_kernel<<<dim3(PB11), 256, 0, stream>>>(
      x, (__hip_bfloat16*)s_x, W_O, (__hip_bfloat16*)wo, rw1, STp, HXQp,
      W_inv, (__hip_bfloat16*)winvT, W_Q, (__hip_bfloat16*)wqT, W_K, (__hip_bfloat16*)wkT,
      V_fwd, W_fwd, W_inv_e, V_inv, XKAp,
      U_fwd, b_fwd, U_inv, b_inv, UTTp);

  // ---- folds: 2 launches, 2 parallel partitions each ----
  {
    FoldArgs f0 = { STp, (const __hip_bfloat16*)winvT,
                    HXQp + (size_t)1024 * BDIM, HXQp + (size_t)2560 * BDIM,
                    XKAp + (size_t)512 * BDIM, 1024, 1536, BDIM, 2048, BDIM, BDIM };
    FoldArgs f1 = { (const __hip_bfloat16*)wo, UTTp,
                    Mcat, nullptr, nullptr, 1 << 30, 1 << 30, PW2, BDIM, PW2, BDIM };
    int n0 = (f0.M / 128) * (f0.N / 128);
    int n1 = (f1.M / 128) * (f1.N / 128);
    gemm_fold2<<<dim3(n0 + n1), 256, 0, stream>>>(f0, f1, n0);
  }
  {
    FoldArgs f0 = { HXQp, (const __hip_bfloat16*)wqT,
                    BigBp, nullptr, nullptr, 1 << 30, 1 << 30, BDIM, 3072, BDIM, BDIM };
    FoldArgs f1 = { XKAp, (const __hip_bfloat16*)wkT,
                    BigBp + (size_t)3072 * BDIM, nullptr, nullptr, 1 << 30, 1 << 30,
                    BDIM, 1024, BDIM, BDIM };
    int n0 = (f0.M / 128) * (f0.N / 128);
    int n1 = (f1.M / 128) * (f1.N / 128);
    gemm_fold2<<<dim3(n0 + n1), 256, 0, stream>>>(f0, f1, n0);
  }

  // ---- ONE merged big GEMM: [Hf|Hi|xVcat|yWcat] = x @ BigB^T (N=4096, EPI=5) ----
  gemm2b(s_x, BigB, Hf, Hi, xVcat, yWcat, 0, 0, 0, BT, 4 * BDIM, BDIM, 5, rb1);

  // ---- merged router + chunksum (one launch) ----
  router_chunksum_kernel<<<dim3(8192 + 1024), 256, 0, stream>>>(
      (const __hip_bfloat16*)Hf, (const __hip_bfloat16*)Hi, rw2, rb2, ebias,
      (float*)wgt_f, (float*)wgt_i, (const __hip_bfloat16*)yWcat, (float*)S);

  // ---- cumsum scan + combine into Pcat ----
  scan_chunks_kernel<<<dim3(4), 1024, 0, stream>>>((float*)S);
  dim3 gch(NCH, 4);
  combine_kernel<<<gch, 1024, 0, stream>>>((const __hip_bfloat16*)yWcat, (const float*)S,
      (const __hip_bfloat16*)xVcat, (const float*)wgt_f, (const float*)wgt_i,
      alphaPtr, (__hip_bfloat16*)Pcat);

  // ---- single output GEMM: out = diag(1/n) * Pcat @ Mcat^T (K=1152) ----
  gemm2b(Pcat, Mcat, d_out, d_out, nullptr, nullptr, BDIM, BDIM, BDIM,
         BT, BDIM, PW2, 4, nullptr);
}

// Round 17
// 444.718 us; speedup vs baseline: 1.1043x; 1.0030x over previous
//
#include <hip/hip_runtime.h>
#include <hip/hip_bf16.h>
#include <math.h>

#define BDIM 1024
#define TDIM 4096
#define BT   16384   // B*T
#define KEXPN 8
#define RRANK 64
#define KR   512     // KEXPN*RRANK
#define PW2  1152    // packed P width: 512 prod_f + 512 prod_i + 8 wf + 8 wi + 112 pad
#define KRC  1024    // concatenated xV/yW width
#define NCH  64
#define TC   64      // T per chunk (NCH*TC == TDIM)

typedef __attribute__((ext_vector_type(8))) short bf16x8;
typedef __attribute__((ext_vector_type(4))) float f32x4;

typedef __attribute__((address_space(1))) char g_char;
typedef __attribute__((address_space(3))) char l_char;

// async 16B global->LDS: per-lane global addr, wave-uniform LDS base (+lane*16 by HW)
__device__ __forceinline__ void gload16(const short* g, short* lds_base_uniform) {
  __builtin_amdgcn_global_load_lds((const g_char*)(const char*)g,
                                   (l_char*)(char*)lds_base_uniform, 16, 0, 0);
}

// ---------------- prep helpers ----------------
__device__ __forceinline__ void cvt4_body(const float* __restrict__ in,
    __hip_bfloat16* __restrict__ out, int blk) {
  long id = (long)blk * 256 + threadIdx.x;
  f32x4 v = ((const f32x4*)in)[id];
  long i = id * 4;
  out[i + 0] = __float2bfloat16(v[0]);
  out[i + 1] = __float2bfloat16(v[1]);
  out[i + 2] = __float2bfloat16(v[2]);
  out[i + 3] = __float2bfloat16(v[3]);
}
__device__ __forceinline__ void transpose_body(const float* __restrict__ in,
    __hip_bfloat16* __restrict__ out, int blk) {
  int id = blk * 256 + threadIdx.x;
  int d = id & (BDIM - 1);
  int e = id >> 10;
  out[(size_t)e * BDIM + d] = __float2bfloat16(in[(size_t)d * BDIM + e]);
}
__device__ __forceinline__ void vmat_body(const float* __restrict__ V,
    __hip_bfloat16* __restrict__ out, int blk) {
  int id = blk * 256 + threadIdx.x;
  int d = id & (BDIM - 1);
  int kr = id >> 10;
  int k = kr >> 6, r = kr & 63;
  out[(size_t)kr * BDIM + d] = __float2bfloat16(V[((size_t)k * BDIM + d) * RRANK + r]);
}
__device__ __forceinline__ void utt_body(const float* __restrict__ Uf,
    const float* __restrict__ bf, const float* __restrict__ Ui,
    const float* __restrict__ bi, __hip_bfloat16* __restrict__ out, int blk) {
  int id = blk * 256 + threadIdx.x;
  if (id >= PW2 * BDIM) return;
  int e = id & (BDIM - 1);
  int c = id >> 10;
  float v = 0.0f;
  if (c < KR) {
    int k = c >> 6, r = c & 63;
    v = Uf[((size_t)k * BDIM + e) * RRANK + r];
  } else if (c < 2 * KR) {
    int c2 = c - KR;
    int k = c2 >> 6, r = c2 & 63;
    v = Ui[((size_t)k * BDIM + e) * RRANK + r];
  } else if (c < 2 * KR + KEXPN) {
    v = bf[(size_t)(c - 2 * KR) * BDIM + e];
  } else if (c < 2 * KR + 2 * KEXPN) {
    v = bi[(size_t)(c - 2 * KR - KEXPN) * BDIM + e];
  }
  out[(size_t)c * BDIM + e] = __float2bfloat16(v);
}

// ---------------- ONE merged prep kernel: 13 partitioned jobs ----------------
#define PB0 16384            // cvt x
#define PB1 (PB0 + 1024)     // cvt W_O
#define PB2 (PB1 + 1024)     // cvt rw1 -> ST
#define PB3 (PB2 + 1024)     // cvt rw1 -> HXQ
#define PB4 (PB3 + 4096)     // transpose W_inv
#define PB5 (PB4 + 4096)     // transpose W_Q
#define PB6 (PB5 + 4096)     // transpose W_K
#define PB7 (PB6 + 2048)     // vmat V_fwd
#define PB8 (PB7 + 2048)     // vmat W_fwd
#define PB9 (PB8 + 2048)     // vmat W_inv_e
#define PB10 (PB9 + 2048)    // vmat V_inv
#define PB11 (PB10 + 4608)   // utt_pack (PW2*BDIM/256)
#define PB12 (PB11 + 1024)   // zero S (4*NCH*KRC floats)
__global__ __launch_bounds__(256) void mega_prep_kernel(
    const float* __restrict__ x,      __hip_bfloat16* __restrict__ s_x,
    const float* __restrict__ W_O,    __hip_bfloat16* __restrict__ wo,
    const float* __restrict__ rw1,    __hip_bfloat16* __restrict__ STp,
    __hip_bfloat16* __restrict__ HXQp,
    const float* __restrict__ W_inv,  __hip_bfloat16* __restrict__ winvT,
    const float* __restrict__ W_Q,    __hip_bfloat16* __restrict__ wqT,
    const float* __restrict__ W_K,    __hip_bfloat16* __restrict__ wkT,
    const float* __restrict__ V_fwd,  const float* __restrict__ W_fwd,
    const float* __restrict__ W_inv_e,const float* __restrict__ V_inv,
    __hip_bfloat16* __restrict__ XKAp,
    const float* __restrict__ U_fwd,  const float* __restrict__ b_fwd,
    const float* __restrict__ U_inv,  const float* __restrict__ b_inv,
    __hip_bfloat16* __restrict__ UTTp, float* __restrict__ S) {
  int b = blockIdx.x;
  if (b < PB0)       cvt4_body(x, s_x, b);
  else if (b < PB1)  cvt4_body(W_O, wo, b - PB0);
  else if (b < PB2)  cvt4_body(rw1, STp, b - PB1);
  else if (b < PB3)  cvt4_body(rw1, HXQp, b - PB2);
  else if (b < PB4)  transpose_body(W_inv, winvT, b - PB3);
  else if (b < PB5)  transpose_body(W_Q, wqT, b - PB4);
  else if (b < PB6)  transpose_body(W_K, wkT, b - PB5);
  else if (b < PB7)  vmat_body(V_fwd, HXQp + (size_t)2048 * BDIM, b - PB6);
  else if (b < PB8)  vmat_body(W_fwd, XKAp, b - PB7);
  else if (b < PB9)  vmat_body(W_inv_e, STp + (size_t)1024 * BDIM, b - PB8);
  else if (b < PB10) vmat_body(V_inv, STp + (size_t)1536 * BDIM, b - PB9);
  else if (b < PB11) utt_body(U_fwd, b_fwd, U_inv, b_inv, UTTp, b - PB10);
  else               S[(size_t)(b - PB11) * 256 + threadIdx.x] = 0.0f;
}

// ================= 128^2 2-phase fold engine, TWO parallel partitions per launch =================
struct FoldArgs {
  const __hip_bfloat16* A; const __hip_bfloat16* B;
  void* C1; void* C2; void* C3;
  int rs1, rs2, ldc, M, N, Kd;
};

__device__ __forceinline__ void fold_body(const FoldArgs fa, int bx, int by,
                                          short* Als, short* Bls) {
  const short* As = (const short*)fa.A;
  const short* Bs = (const short*)fa.B;
  const int Kd = fa.Kd;
  const int t  = threadIdx.x;
  const int w  = t >> 6;
  const int l  = t & 63;
  const int lr = l & 15;
  const int lk = l >> 4;
  const int wr = w >> 1;
  const int wc = w & 1;
  const int row0 = by * 128;
  const int col0 = bx * 128;
  const int srow = w * 16 + (l >> 2);
  const int scol = (l & 3) * 8;
  const short* ag0 = As + (size_t)(row0 + srow) * Kd + scol;
  const short* ag1 = As + (size_t)(row0 + 64 + srow) * Kd + scol;
  const short* bg0 = Bs + (size_t)(col0 + srow) * Kd + scol;
  const short* bg1 = Bs + (size_t)(col0 + 64 + srow) * Kd + scol;
  f32x4 acc[4][4] = {};
  const int nt = Kd / 32;
  auto stage = [&](int kt, int buf) {
    int k0 = kt * 32;
    gload16(ag0 + k0, Als + buf * 4096 + w * 512);
    gload16(ag1 + k0, Als + buf * 4096 + 2048 + w * 512);
    gload16(bg0 + k0, Bls + buf * 4096 + w * 512);
    gload16(bg1 + k0, Bls + buf * 4096 + 2048 + w * 512);
  };
  stage(0, 0);
  __syncthreads();
  int cur = 0;
  for (int kt = 0; kt < nt; ++kt) {
    if (kt + 1 < nt) stage(kt + 1, cur ^ 1);
    bf16x8 af[4], bfr[4];
    #pragma unroll
    for (int i = 0; i < 4; i++)
      af[i] = *(const bf16x8*)&Als[cur * 4096 + (wr * 64 + i * 16 + lr) * 32 + lk * 8];
    #pragma unroll
    for (int j = 0; j < 4; j++)
      bfr[j] = *(const bf16x8*)&Bls[cur * 4096 + (wc * 64 + j * 16 + lr) * 32 + lk * 8];
    #pragma unroll
    for (int i = 0; i < 4; i++)
      #pragma unroll
      for (int j = 0; j < 4; j++)
        acc[i][j] = __builtin_amdgcn_mfma_f32_16x16x32_bf16(af[i], bfr[j], acc[i][j], 0, 0, 0);
    __syncthreads();
    cur ^= 1;
  }
  #pragma unroll
  for (int i = 0; i < 4; i++)
    #pragma unroll
    for (int j = 0; j < 4; j++)
      #pragma unroll
      for (int g = 0; g < 4; g++) {
        int r = row0 + wr * 64 + i * 16 + lk * 4 + g;
        int c = col0 + wc * 64 + j * 16 + lr;
        void* dst = fa.C1; int rr = r;
        if (r >= fa.rs2)      { dst = fa.C3; rr = r - fa.rs2; }
        else if (r >= fa.rs1) { dst = fa.C2; rr = r - fa.rs1; }
        ((__hip_bfloat16*)dst)[(size_t)rr * fa.ldc + c] = __float2bfloat16(acc[i][j][g]);
      }
}

__global__ __launch_bounds__(256) void gemm_fold2(FoldArgs fa0, FoldArgs fa1, int nblk0) {
  __shared__ __align__(16) short Als[2 * 128 * 32];
  __shared__ __align__(16) short Bls[2 * 128 * 32];
  int id = blockIdx.x;
  if (id < nblk0) {
    int nbx = fa0.N / 128;
    fold_body(fa0, id % nbx, id / nbx, Als, Bls);
  } else {
    int lid = id - nblk0;
    int nbx = fa1.N / 128;
    fold_body(fa1, lid % nbx, lid / nbx, Als, Bls);
  }
}

// ================= 256^2 4-phase BK=64 engine (big GEMMs) — R13 schedule =================
// EPI: 4 = /n_valid->f32, 5 = 4-seg merged (gelu|gelu|bf16|bf16) + seg3 chunk-sum atomics
template<int EPI>
__global__ __launch_bounds__(512, 2) void gemm_nt_256(const __hip_bfloat16* __restrict__ A,
    const __hip_bfloat16* __restrict__ B, void* __restrict__ Cv, void* __restrict__ Cv2,
    void* __restrict__ Cv3, void* __restrict__ Cv4,
    int csplit, int ldc, int ldc2, const float* __restrict__ bias,
    float* __restrict__ Sp, int M, int N, int Kd) {
  __shared__ __align__(16) short Als[2][2][256 * 32];   // [buf][kh] 64 KB
  __shared__ __align__(16) short Bls[2][2][256 * 32];   // 64 KB

  int nbx = gridDim.x;
  int nwg = nbx * gridDim.y;
  int bx = blockIdx.x, by = blockIdx.y;
  if ((nwg & 7) == 0) {
    int orig = by * nbx + bx;
    int cpx = nwg >> 3;
    int id = (orig & 7) * cpx + (orig >> 3);
    bx = id % nbx; by = id / nbx;
  }
  const short* As = (const short*)A;
  const short* Bs = (const short*)B;
  const int t  = threadIdx.x;      // 0..511
  const int w  = t >> 6;           // 0..7
  const int l  = t & 63;
  const int lr = l & 15;
  const int lk = l >> 4;
  const int wr = w >> 2;           // 0..1 (M half)
  const int wc = w & 3;            // 0..3 (N quarter)
  const int row0 = by * 256;
  const int col0 = bx * 256;

  const int srow  = t >> 2;                       // 0..127
  const int sslot = (t & 3) ^ ((srow >> 1) & 3);
  const short* agA0 = As + (size_t)(row0 + srow) * Kd + sslot * 8;
  const short* agA1 = As + (size_t)(row0 + 128 + srow) * Kd + sslot * 8;
  const short* bgB0 = Bs + (size_t)(col0 + srow) * Kd + sslot * 8;
  const short* bgB1 = Bs + (size_t)(col0 + 128 + srow) * Kd + sslot * 8;

  auto stageA = [&](int buf, int kh, int kt) {
    int k0 = kt * 64 + kh * 32;
    short* base = &Als[buf][kh][0];
    gload16(agA0 + k0, base + w * 512);
    gload16(agA1 + k0, base + 4096 + w * 512);
  };
  auto stageB = [&](int buf, int kh, int kt) {
    int k0 = kt * 64 + kh * 32;
    short* base = &Bls[buf][kh][0];
    gload16(bgB0 + k0, base + w * 512);
    gload16(bgB1 + k0, base + 4096 + w * 512);
  };

  int aoff[8], boff[4];
  #pragma unroll
  for (int mf = 0; mf < 8; ++mf) {
    int r = wr * 128 + mf * 16 + lr;
    aoff[mf] = r * 32 + ((lk ^ ((r >> 1) & 3)) << 3);
  }
  #pragma unroll
  for (int nf = 0; nf < 4; ++nf) {
    int r = wc * 64 + nf * 16 + lr;
    boff[nf] = r * 32 + ((lk ^ ((r >> 1) & 3)) << 3);
  }

  f32x4 acc[8][4] = {};
  const int NT = Kd >> 6;   // K-tiles of 64

  stageA(0, 0, 0); stageA(0, 1, 0); stageB(0, 0, 0); stageB(0, 1, 0);
  asm volatile("s_waitcnt vmcnt(0)" ::: "memory");
  __builtin_amdgcn_sched_barrier(0);
  __builtin_amdgcn_s_barrier();

  for (int kt = 0; kt < NT; ++kt) {
    const int buf = kt & 1, nb = buf ^ 1;
    const short* A0 = &Als[buf][0][0];
    const short* A1 = &Als[buf][1][0];
    const short* B0 = &Bls[buf][0][0];
    const short* B1 = &Bls[buf][1][0];
    const bool st = (kt + 1 < NT);
    bf16x8 af[4], bfr[4];

    // ---- phase 1: kh0, M-half 0 ----
    #pragma unroll
    for (int i = 0; i < 4; ++i) bfr[i] = *(const bf16x8*)&B0[boff[i]];
    #pragma unroll
    for (int i = 0; i < 4; ++i) af[i]  = *(const bf16x8*)&A0[aoff[i]];
    if (st) { stageA(nb, 0, kt + 1); stageA(nb, 1, kt + 1); }
    __builtin_amdgcn_s_barrier();
    __builtin_amdgcn_s_setprio(1);
    #pragma unroll
    for (int i = 0; i < 4; ++i)
      #pragma unroll
      for (int j = 0; j < 4; ++j)
        acc[i][j] = __builtin_amdgcn_mfma_f32_16x16x32_bf16(af[i], bfr[j], acc[i][j], 0, 0, 0);
    __builtin_amdgcn_s_setprio(0);
    __builtin_amdgcn_s_barrier();

    // ---- phase 2: kh0, M-half 1 (B reused) ----
    #pragma unroll
    for (int i = 0; i < 4; ++i) af[i] = *(const bf16x8*)&A0[aoff[4 + i]];
    if (st) { stageB(nb, 0, kt + 1); stageB(nb, 1, kt + 1); }
    __builtin_amdgcn_s_barrier();
    __builtin_amdgcn_s_setprio(1);
    #pragma unroll
    for (int i = 0; i < 4; ++i)
      #pragma unroll
      for (int j = 0; j < 4; ++j)
        acc[4 + i][j] = __builtin_amdgcn_mfma_f32_16x16x32_bf16(af[i], bfr[j], acc[4 + i][j], 0, 0, 0);
    __builtin_amdgcn_s_setprio(0);
    __builtin_amdgcn_s_barrier();

    // ---- phase 3: kh1, M-half 0 ----
    #pragma unroll
    for (int i = 0; i < 4; ++i) bfr[i] = *(const bf16x8*)&B1[boff[i]];
    #pragma unroll
    for (int i = 0; i < 4; ++i) af[i]  = *(const bf16x8*)&A1[aoff[i]];
    __builtin_amdgcn_s_barrier();
    __builtin_amdgcn_s_setprio(1);
    #pragma unroll
    for (int i = 0; i < 4; ++i)
      #pragma unroll
      for (int j = 0; j < 4; ++j)
        acc[i][j] = __builtin_amdgcn_mfma_f32_16x16x32_bf16(af[i], bfr[j], acc[i][j], 0, 0, 0);
    __builtin_amdgcn_s_setprio(0);
    __builtin_amdgcn_s_barrier();

    // ---- phase 4: kh1, M-half 1 ----
    #pragma unroll
    for (int i = 0; i < 4; ++i) af[i] = *(const bf16x8*)&A1[aoff[4 + i]];
    __builtin_amdgcn_s_barrier();
    __builtin_amdgcn_s_setprio(1);
    #pragma unroll
    for (int i = 0; i < 4; ++i)
      #pragma unroll
      for (int j = 0; j < 4; ++j)
        acc[4 + i][j] = __builtin_amdgcn_mfma_f32_16x16x32_bf16(af[i], bfr[j], acc[4 + i][j], 0, 0, 0);
    __builtin_amdgcn_s_setprio(0);
    asm volatile("s_waitcnt vmcnt(0)" ::: "memory");
    __builtin_amdgcn_sched_barrier(0);
    __builtin_amdgcn_s_barrier();
  }

  #pragma unroll
  for (int mf = 0; mf < 8; ++mf)
    #pragma unroll
    for (int nf = 0; nf < 4; ++nf)
      #pragma unroll
      for (int g = 0; g < 4; ++g) {
        int r = row0 + wr * 128 + mf * 16 + lk * 4 + g;
        int c = col0 + wc * 64 + nf * 16 + lr;
        float v = acc[mf][nf][g];
        if (EPI == 5) {
          int seg = c >> 10;
          int cc = c & (BDIM - 1);
          void* dst = seg == 0 ? Cv : (seg == 1 ? Cv2 : (seg == 2 ? Cv3 : Cv4));
          if (seg < 2) {
            float xv = v + bias[cc];
            v = 0.5f * xv * (1.0f + erff(xv * 0.70710678118654752f));
          }
          ((__hip_bfloat16*)dst)[(size_t)r * BDIM + cc] = __float2bfloat16(v);
        } else {
          void* dst = Cv;
          int cc = c, ld = ldc;
          if (c >= csplit) { dst = Cv2; cc = c - csplit; ld = ldc2; }
          size_t idx = (size_t)r * ld + cc;
          float s = 1.0f / (float)((r & (TDIM - 1)) + 1);
          ((float*)dst)[idx] = v * s;
        }
      }

  // ---- fused chunk-sum for seg 3 (yW): per-thread partials + 8 atomics/thread ----
  if (EPI == 5 && (col0 >> 10) == 3) {
    #pragma unroll
    for (int half = 0; half < 2; ++half) {
      int rbase = row0 + wr * 128 + half * 64;     // 64-aligned chunk start
      int b  = rbase >> 12;                        // / TDIM
      int ch = (rbase & (TDIM - 1)) >> 6;
      #pragma unroll
      for (int nf = 0; nf < 4; ++nf) {
        float s = 0.0f;
        #pragma unroll
        for (int mf = half * 4; mf < half * 4 + 4; ++mf)
          #pragma unroll
          for (int g = 0; g < 4; ++g) s += acc[mf][nf][g];
        int j = (col0 - 3 * BDIM) + wc * 64 + nf * 16 + lr;
        atomicAdd(&Sp[((size_t)b * NCH + ch) * KRC + j], s);
      }
    }
  }
}

// ---------------- router (vectorized bf16x8 loads; 8192 blocks, branch = blk>>12) ----------------
__global__ __launch_bounds__(256) void router_kernel(
    const __hip_bfloat16* __restrict__ Hf, const __hip_bfloat16* __restrict__ Hi,
    const float* __restrict__ w2, const float* __restrict__ b2,
    const float* __restrict__ ebias, float* __restrict__ wgt_f, float* __restrict__ wgt_i) {
  int blk = blockIdx.x;
  const __hip_bfloat16* H = (blk >> 12) ? Hi : Hf;
  float* wgt = (blk >> 12) ? wgt_i : wgt_f;
  int rowblk = blk & 4095;
  int wv = threadIdx.x >> 6;
  int l  = threadIdx.x & 63;
  int row = rowblk * 4 + wv;
  const short* Hs = (const short*)H;
  float acc[KEXPN] = {};
  #pragma unroll
  for (int i = 0; i < BDIM / 512; i++) {
    int h = (i * 64 + l) * 8;
    bf16x8 hv = *(const bf16x8*)(Hs + (size_t)row * BDIM + h);
    #pragma unroll
    for (int j = 0; j < 8; j++) {
      unsigned int ui = ((unsigned int)(unsigned short)hv[j]) << 16;
      float xv = __uint_as_float(ui);
      #pragma unroll
      for (int k = 0; k < KEXPN; k++) acc[k] += xv * w2[k * BDIM + h + j];
    }
  }
  #pragma unroll
  for (int k = 0; k < KEXPN; k++)
    for (int off = 32; off; off >>= 1) acc[k] += __shfl_down(acc[k], off);
  if (l == 0) {
    float lg[KEXPN];
    float mx = -1e30f;
    #pragma unroll
    for (int k = 0; k < KEXPN; k++) { lg[k] = acc[k] + b2[k] + ebias[k]; mx = fmaxf(mx, lg[k]); }
    float s = 0.0f;
    #pragma unroll
    for (int k = 0; k < KEXPN; k++) { lg[k] = expf(lg[k] - mx); s += lg[k]; }
    float inv = 1.0f / s;
    #pragma unroll
    for (int k = 0; k < KEXPN; k++) wgt[(size_t)row * KEXPN + k] = lg[k] * inv;
  }
}

// ---------------- cumsum phase 2: exclusive scan of chunk sums (in place) ----------------
__global__ __launch_bounds__(1024) void scan_chunks_kernel(float* __restrict__ S) {
  int j = threadIdx.x;
  int b = blockIdx.x;
  float run = 0.0f;
  for (int ch = 0; ch < NCH; ch++) {
    size_t i = ((size_t)b * NCH + ch) * KRC + j;
    float v = S[i];
    S[i] = run;
    run += v;
  }
}

// ---------------- cumsum phase 3 + combine both branches -> Pcat (+ ext cols fused) ----------------
__global__ __launch_bounds__(1024) void combine_kernel(const __hip_bfloat16* __restrict__ yW,
    const float* __restrict__ S, const __hip_bfloat16* __restrict__ xV,
    const float* __restrict__ wf, const float* __restrict__ wi,
    const float* __restrict__ alphaPtr, __hip_bfloat16* __restrict__ P) {
  int j  = threadIdx.x;
  int ch = blockIdx.x;
  int b  = blockIdx.y;
  float alpha = alphaPtr[0];
  float scale = (j < KR) ? 1.0f : alpha;
  const float* wgt = (j < KR) ? wf : wi;
  int k = (j & (KR - 1)) >> 6;
  float run = S[((size_t)b * NCH + ch) * KRC + j];
  for (int t0 = 0; t0 < TC; t0++) {
    size_t row = (size_t)b * TDIM + ch * TC + t0;
    run += __bfloat162float(yW[row * KRC + j]);
    float p = __bfloat162float(xV[row * KRC + j]) * run * wgt[row * KEXPN + k] * scale;
    P[row * PW2 + j] = __float2bfloat16(p);
  }
  if (j < 128) {
    int col = KRC + j;
    for (int t0 = 0; t0 < TC; t0++) {
      size_t row = (size_t)b * TDIM + ch * TC + t0;
      float v = 0.0f;
      if (j < KEXPN)          v = wf[row * KEXPN + j];
      else if (j < 2 * KEXPN) v = wi[row * KEXPN + (j - KEXPN)] * alpha;
      P[row * PW2 + col] = __float2bfloat16(v);
    }
  }
}

// ---------------- sentinel ----------------
__global__ __launch_bounds__(256) void fill_kernel(float* __restrict__ out, long n, float val) {
  long id = (long)blockIdx.x * 256 + threadIdx.x;
  if (id < n) out[id] = val;
}

extern "C" void kernel_launch(void* const* d_in, const int* in_sizes, int n_in,
                              void* d_out, int out_size, void* d_ws, size_t ws_size,
                              hipStream_t stream) {
  const float* x        = (const float*)d_in[0];
  const float* W_Q      = (const float*)d_in[1];
  const float* W_K      = (const float*)d_in[2];
  const float* W_O      = (const float*)d_in[3];
  const float* W_inv    = (const float*)d_in[4];
  const float* V_fwd    = (const float*)d_in[5];
  const float* W_fwd    = (const float*)d_in[6];
  const float* U_fwd    = (const float*)d_in[7];
  const float* b_fwd    = (const float*)d_in[8];
  const float* V_inv    = (const float*)d_in[9];
  const float* W_inv_e  = (const float*)d_in[10];
  const float* U_inv    = (const float*)d_in[11];
  const float* b_inv    = (const float*)d_in[12];
  const float* rw1      = (const float*)d_in[13];
  const float* rb1      = (const float*)d_in[14];
  const float* rw2      = (const float*)d_in[15];
  const float* rb2      = (const float*)d_in[16];
  const float* alphaPtr = (const float*)d_in[17];
  const float* ebias    = (const float*)d_in[18];

  char* ws = (char*)d_ws;
  size_t off = 0;
  auto alloc = [&](size_t sz) -> void* {
    void* p = ws + off;
    off += (sz + 255) & ~(size_t)255;
    return p;
  };

  const size_t RB = (size_t)BDIM * 2;
  void* winvT = alloc((size_t)BDIM * RB);
  void* wqT   = alloc((size_t)BDIM * RB);
  void* wkT   = alloc((size_t)BDIM * RB);
  void* wo    = alloc((size_t)BDIM * RB);
  void* ST    = alloc((size_t)2048 * RB);
  void* HXQ   = alloc((size_t)3072 * RB);
  void* XKA   = alloc((size_t)1024 * RB);
  void* BigB  = alloc((size_t)4096 * RB);
  void* UTT   = alloc((size_t)PW2 * RB);
  void* Mcat  = alloc((size_t)BDIM * PW2 * 2);
  void* wgt_f = alloc((size_t)BT * KEXPN * 4);
  void* wgt_i = alloc((size_t)BT * KEXPN * 4);
  void* S     = alloc((size_t)4 * NCH * KRC * 4);
  void* s_x   = alloc((size_t)BT * BDIM * 2);
  void* Hf    = alloc((size_t)BT * BDIM * 2);
  void* Hi    = alloc((size_t)BT * BDIM * 2);
  void* xVcat = alloc((size_t)BT * KRC * 2);
  void* yWcat = alloc((size_t)BT * KRC * 2);
  void* Pcat  = Hf;

  if (off > ws_size) {
    fill_kernel<<<dim3((unsigned)((out_size + 255) / 256)), 256, 0, stream>>>(
        (float*)d_out, (long)out_size, (float)(off >> 20));
    return;
  }

  __hip_bfloat16* STp  = (__hip_bfloat16*)ST;
  __hip_bfloat16* HXQp = (__hip_bfloat16*)HXQ;
  __hip_bfloat16* XKAp = (__hip_bfloat16*)XKA;
  __hip_bfloat16* BigBp= (__hip_bfloat16*)BigB;
  __hip_bfloat16* UTTp = (__hip_bfloat16*)UTT;

  auto gemm2b = [&](const void* A, const void* Bm, void* C, void* C2, void* C3, void* C4,
                    int csplit, int ldc, int ldc2, int M, int N, int Kd, int epi,
                    const float* bias) {
    dim3 g(N / 256, M / 256);
    if (epi == 5) gemm_nt_256<5><<<g, 512, 0, stream>>>((const __hip_bfloat16*)A, (const __hip_bfloat16*)Bm, C, C2, C3, C4, csplit, ldc, ldc2, bias, (float*)S, M, N, Kd);
    else          gemm_nt_256<4><<<g, 512, 0, stream>>>((const __hip_bfloat16*)A, (const __hip_bfloat16*)Bm, C, C2, C3, C4, csplit, ldc, ldc2, bias, (float*)S, M, N, Kd);
  };

  // ---- ONE merged prep launch (13 partitioned jobs, incl. S zeroing) ----
  mega_prep_kernel<<<dim3(PB12), 256, 0, stream>>>(
      x, (__hip_bfloat16*)s_x, W_O, (__hip_bfloat16*)wo, rw1, STp, HXQp,
      W_inv, (__hip_bfloat16*)winvT, W_Q, (__hip_bfloat16*)wqT, W_K, (__hip_bfloat16*)wkT,
      V_fwd, W_fwd, W_inv_e, V_inv, XKAp,
      U_fwd, b_fwd, U_inv, b_inv, UTTp, (float*)S);

  // ---- folds: 2 launches, 2 parallel partitions each ----
  {
    FoldArgs f0 = { STp, (const __hip_bfloat16*)winvT,
                    HXQp + (size_t)1024 * BDIM, HXQp + (size_t)2560 * BDIM,
                    XKAp + (size_t)512 * BDIM, 1024, 1536, BDIM, 2048, BDIM, BDIM };
    FoldArgs f1 = { (const __hip_bfloat16*)wo, UTTp,
                    Mcat, nullptr, nullptr, 1 << 30, 1 << 30, PW2, BDIM, PW2, BDIM };
    int n0 = (f0.M / 128) * (f0.N / 128);
    int n1 = (f1.M / 128) * (f1.N / 128);
    gemm_fold2<<<dim3(n0 + n1), 256, 0, stream>>>(f0, f1, n0);
  }
  {
    FoldArgs f0 = { HXQp, (const __hip_bfloat16*)wqT,
                    BigBp, nullptr, nullptr, 1 << 30, 1 << 30, BDIM, 3072, BDIM, BDIM };
    FoldArgs f1 = { XKAp, (const __hip_bfloat16*)wkT,
                    BigBp + (size_t)3072 * BDIM, nullptr, nullptr, 1 << 30, 1 << 30,
                    BDIM, 1024, BDIM, BDIM };
    int n0 = (f0.M / 128) * (f0.N / 128);
    int n1 = (f1.M / 128) * (f1.N / 128);
    gemm_fold2<<<dim3(n0 + n1), 256, 0, stream>>>(f0, f1, n0);
  }

  // ---- ONE merged big GEMM: [Hf|Hi|xVcat|yWcat] = x @ BigB^T (N=4096, EPI=5 + chunksum) ----
  gemm2b(s_x, BigB, Hf, Hi, xVcat, yWcat, 0, 0, 0, BT, 4 * BDIM, BDIM, 5, rb1);

  // ---- router ----
  router_kernel<<<dim3(8192), 256, 0, stream>>>(
      (const __hip_bfloat16*)Hf, (const __hip_bfloat16*)Hi, rw2, rb2, ebias,
      (float*)wgt_f, (float*)wgt_i);

  // ---- cumsum scan + combine into Pcat ----
  scan_chunks_kernel<<<dim3(4), 1024, 0, stream>>>((float*)S);
  dim3 gch(NCH, 4);
  combine_kernel<<<gch, 1024, 0, stream>>>((const __hip_bfloat16*)yWcat, (const float*)S,
      (const __hip_bfloat16*)xVcat, (const float*)wgt_f, (const float*)wgt_i,
      alphaPtr, (__hip_bfloat16*)Pcat);

  // ---- single output GEMM: out = diag(1/n) * Pcat @ Mcat^T (K=1152) ----
  gemm2b(Pcat, Mcat, d_out, d_out, nullptr, nullptr, BDIM, BDIM, BDIM,
         BT, BDIM, PW2, 4, nullptr);
}

// Round 18
// 436.102 us; speedup vs baseline: 1.1261x; 1.0198x over previous
//
#include <hip/hip_runtime.h>
#include <hip/hip_bf16.h>
#include <math.h>

#define BDIM 1024
#define TDIM 4096
#define BT   16384   // B*T
#define KEXPN 8
#define RRANK 64
#define KR   512     // KEXPN*RRANK
#define PW2  1152    // packed P width: 512 prod_f + 512 prod_i + 8 wf + 8 wi + 112 pad
#define KRC  1024    // concatenated xV/yW width
#define NCH  64
#define TC   64      // T per chunk (NCH*TC == TDIM)

typedef __attribute__((ext_vector_type(8))) short bf16x8;
typedef __attribute__((ext_vector_type(4))) float f32x4;

typedef __attribute__((address_space(1))) char g_char;
typedef __attribute__((address_space(3))) char l_char;

// async 16B global->LDS: per-lane global addr, wave-uniform LDS base (+lane*16 by HW)
__device__ __forceinline__ void gload16(const short* g, short* lds_base_uniform) {
  __builtin_amdgcn_global_load_lds((const g_char*)(const char*)g,
                                   (l_char*)(char*)lds_base_uniform, 16, 0, 0);
}

// ---------------- prep helpers ----------------
__device__ __forceinline__ void cvt4_body(const float* __restrict__ in,
    __hip_bfloat16* __restrict__ out, int blk) {
  long id = (long)blk * 256 + threadIdx.x;
  f32x4 v = ((const f32x4*)in)[id];
  long i = id * 4;
  out[i + 0] = __float2bfloat16(v[0]);
  out[i + 1] = __float2bfloat16(v[1]);
  out[i + 2] = __float2bfloat16(v[2]);
  out[i + 3] = __float2bfloat16(v[3]);
}
__device__ __forceinline__ void transpose_body(const float* __restrict__ in,
    __hip_bfloat16* __restrict__ out, int blk) {
  int id = blk * 256 + threadIdx.x;
  int d = id & (BDIM - 1);
  int e = id >> 10;
  out[(size_t)e * BDIM + d] = __float2bfloat16(in[(size_t)d * BDIM + e]);
}
__device__ __forceinline__ void vmat_body(const float* __restrict__ V,
    __hip_bfloat16* __restrict__ out, int blk) {
  int id = blk * 256 + threadIdx.x;
  int d = id & (BDIM - 1);
  int kr = id >> 10;
  int k = kr >> 6, r = kr & 63;
  out[(size_t)kr * BDIM + d] = __float2bfloat16(V[((size_t)k * BDIM + d) * RRANK + r]);
}
__device__ __forceinline__ void utt_body(const float* __restrict__ Uf,
    const float* __restrict__ bf, const float* __restrict__ Ui,
    const float* __restrict__ bi, __hip_bfloat16* __restrict__ out, int blk) {
  int id = blk * 256 + threadIdx.x;
  if (id >= PW2 * BDIM) return;
  int e = id & (BDIM - 1);
  int c = id >> 10;
  float v = 0.0f;
  if (c < KR) {
    int k = c >> 6, r = c & 63;
    v = Uf[((size_t)k * BDIM + e) * RRANK + r];
  } else if (c < 2 * KR) {
    int c2 = c - KR;
    int k = c2 >> 6, r = c2 & 63;
    v = Ui[((size_t)k * BDIM + e) * RRANK + r];
  } else if (c < 2 * KR + KEXPN) {
    v = bf[(size_t)(c - 2 * KR) * BDIM + e];
  } else if (c < 2 * KR + 2 * KEXPN) {
    v = bi[(size_t)(c - 2 * KR - KEXPN) * BDIM + e];
  }
  out[(size_t)c * BDIM + e] = __float2bfloat16(v);
}

// ---------------- ONE merged prep kernel: 13 partitioned jobs ----------------
#define PB0 16384            // cvt x
#define PB1 (PB0 + 1024)     // cvt W_O
#define PB2 (PB1 + 1024)     // cvt rw1 -> ST
#define PB3 (PB2 + 1024)     // cvt rw1 -> HXQ
#define PB4 (PB3 + 4096)     // transpose W_inv
#define PB5 (PB4 + 4096)     // transpose W_Q
#define PB6 (PB5 + 4096)     // transpose W_K
#define PB7 (PB6 + 2048)     // vmat V_fwd
#define PB8 (PB7 + 2048)     // vmat W_fwd
#define PB9 (PB8 + 2048)     // vmat W_inv_e
#define PB10 (PB9 + 2048)    // vmat V_inv
#define PB11 (PB10 + 4608)   // utt_pack (PW2*BDIM/256)
#define PB12 (PB11 + 1024)   // zero S (4*NCH*KRC floats)
__global__ __launch_bounds__(256) void mega_prep_kernel(
    const float* __restrict__ x,      __hip_bfloat16* __restrict__ s_x,
    const float* __restrict__ W_O,    __hip_bfloat16* __restrict__ wo,
    const float* __restrict__ rw1,    __hip_bfloat16* __restrict__ STp,
    __hip_bfloat16* __restrict__ HXQp,
    const float* __restrict__ W_inv,  __hip_bfloat16* __restrict__ winvT,
    const float* __restrict__ W_Q,    __hip_bfloat16* __restrict__ wqT,
    const float* __restrict__ W_K,    __hip_bfloat16* __restrict__ wkT,
    const float* __restrict__ V_fwd,  const float* __restrict__ W_fwd,
    const float* __restrict__ W_inv_e,const float* __restrict__ V_inv,
    __hip_bfloat16* __restrict__ XKAp,
    const float* __restrict__ U_fwd,  const float* __restrict__ b_fwd,
    const float* __restrict__ U_inv,  const float* __restrict__ b_inv,
    __hip_bfloat16* __restrict__ UTTp, float* __restrict__ S) {
  int b = blockIdx.x;
  if (b < PB0)       cvt4_body(x, s_x, b);
  else if (b < PB1)  cvt4_body(W_O, wo, b - PB0);
  else if (b < PB2)  cvt4_body(rw1, STp, b - PB1);
  else if (b < PB3)  cvt4_body(rw1, HXQp, b - PB2);
  else if (b < PB4)  transpose_body(W_inv, winvT, b - PB3);
  else if (b < PB5)  transpose_body(W_Q, wqT, b - PB4);
  else if (b < PB6)  transpose_body(W_K, wkT, b - PB5);
  else if (b < PB7)  vmat_body(V_fwd, HXQp + (size_t)2048 * BDIM, b - PB6);
  else if (b < PB8)  vmat_body(W_fwd, XKAp, b - PB7);
  else if (b < PB9)  vmat_body(W_inv_e, STp + (size_t)1024 * BDIM, b - PB8);
  else if (b < PB10) vmat_body(V_inv, STp + (size_t)1536 * BDIM, b - PB9);
  else if (b < PB11) utt_body(U_fwd, b_fwd, U_inv, b_inv, UTTp, b - PB10);
  else               S[(size_t)(b - PB11) * 256 + threadIdx.x] = 0.0f;
}

// ================= 128^2 2-phase fold engine, TWO parallel partitions per launch =================
struct FoldArgs {
  const __hip_bfloat16* A; const __hip_bfloat16* B;
  void* C1; void* C2; void* C3;
  int rs1, rs2, ldc, M, N, Kd;
};

__device__ __forceinline__ void fold_body(const FoldArgs fa, int bx, int by,
                                          short* Als, short* Bls) {
  const short* As = (const short*)fa.A;
  const short* Bs = (const short*)fa.B;
  const int Kd = fa.Kd;
  const int t  = threadIdx.x;
  const int w  = t >> 6;
  const int l  = t & 63;
  const int lr = l & 15;
  const int lk = l >> 4;
  const int wr = w >> 1;
  const int wc = w & 1;
  const int row0 = by * 128;
  const int col0 = bx * 128;
  const int srow = w * 16 + (l >> 2);
  const int scol = (l & 3) * 8;
  const short* ag0 = As + (size_t)(row0 + srow) * Kd + scol;
  const short* ag1 = As + (size_t)(row0 + 64 + srow) * Kd + scol;
  const short* bg0 = Bs + (size_t)(col0 + srow) * Kd + scol;
  const short* bg1 = Bs + (size_t)(col0 + 64 + srow) * Kd + scol;
  f32x4 acc[4][4] = {};
  const int nt = Kd / 32;
  auto stage = [&](int kt, int buf) {
    int k0 = kt * 32;
    gload16(ag0 + k0, Als + buf * 4096 + w * 512);
    gload16(ag1 + k0, Als + buf * 4096 + 2048 + w * 512);
    gload16(bg0 + k0, Bls + buf * 4096 + w * 512);
    gload16(bg1 + k0, Bls + buf * 4096 + 2048 + w * 512);
  };
  stage(0, 0);
  __syncthreads();
  int cur = 0;
  for (int kt = 0; kt < nt; ++kt) {
    if (kt + 1 < nt) stage(kt + 1, cur ^ 1);
    bf16x8 af[4], bfr[4];
    #pragma unroll
    for (int i = 0; i < 4; i++)
      af[i] = *(const bf16x8*)&Als[cur * 4096 + (wr * 64 + i * 16 + lr) * 32 + lk * 8];
    #pragma unroll
    for (int j = 0; j < 4; j++)
      bfr[j] = *(const bf16x8*)&Bls[cur * 4096 + (wc * 64 + j * 16 + lr) * 32 + lk * 8];
    #pragma unroll
    for (int i = 0; i < 4; i++)
      #pragma unroll
      for (int j = 0; j < 4; j++)
        acc[i][j] = __builtin_amdgcn_mfma_f32_16x16x32_bf16(af[i], bfr[j], acc[i][j], 0, 0, 0);
    __syncthreads();
    cur ^= 1;
  }
  #pragma unroll
  for (int i = 0; i < 4; i++)
    #pragma unroll
    for (int j = 0; j < 4; j++)
      #pragma unroll
      for (int g = 0; g < 4; g++) {
        int r = row0 + wr * 64 + i * 16 + lk * 4 + g;
        int c = col0 + wc * 64 + j * 16 + lr;
        void* dst = fa.C1; int rr = r;
        if (r >= fa.rs2)      { dst = fa.C3; rr = r - fa.rs2; }
        else if (r >= fa.rs1) { dst = fa.C2; rr = r - fa.rs1; }
        ((__hip_bfloat16*)dst)[(size_t)rr * fa.ldc + c] = __float2bfloat16(acc[i][j][g]);
      }
}

__global__ __launch_bounds__(256) void gemm_fold2(FoldArgs fa0, FoldArgs fa1, int nblk0) {
  __shared__ __align__(16) short Als[2 * 128 * 32];
  __shared__ __align__(16) short Bls[2 * 128 * 32];
  int id = blockIdx.x;
  if (id < nblk0) {
    int nbx = fa0.N / 128;
    fold_body(fa0, id % nbx, id / nbx, Als, Bls);
  } else {
    int lid = id - nblk0;
    int nbx = fa1.N / 128;
    fold_body(fa1, lid % nbx, lid / nbx, Als, Bls);
  }
}

// ================= 256^2 4-phase BK=64 engine (big GEMMs) — R13 schedule =================
// EPI: 4 = /n_valid->f32, 5 = 4-seg merged (gelu|gelu|bf16|bf16) + seg3 chunk-sum atomics
template<int EPI>
__global__ __launch_bounds__(512, 2) void gemm_nt_256(const __hip_bfloat16* __restrict__ A,
    const __hip_bfloat16* __restrict__ B, void* __restrict__ Cv, void* __restrict__ Cv2,
    void* __restrict__ Cv3, void* __restrict__ Cv4,
    int csplit, int ldc, int ldc2, const float* __restrict__ bias,
    float* __restrict__ Sp, int M, int N, int Kd) {
  __shared__ __align__(16) short Als[2][2][256 * 32];   // [buf][kh] 64 KB
  __shared__ __align__(16) short Bls[2][2][256 * 32];   // 64 KB

  int nbx = gridDim.x;
  int nwg = nbx * gridDim.y;
  int bx = blockIdx.x, by = blockIdx.y;
  if ((nwg & 7) == 0) {
    int orig = by * nbx + bx;
    int cpx = nwg >> 3;
    int id = (orig & 7) * cpx + (orig >> 3);
    bx = id % nbx; by = id / nbx;
  }
  const short* As = (const short*)A;
  const short* Bs = (const short*)B;
  const int t  = threadIdx.x;      // 0..511
  const int w  = t >> 6;           // 0..7
  const int l  = t & 63;
  const int lr = l & 15;
  const int lk = l >> 4;
  const int wr = w >> 2;           // 0..1 (M half)
  const int wc = w & 3;            // 0..3 (N quarter)
  const int row0 = by * 256;
  const int col0 = bx * 256;

  const int srow  = t >> 2;                       // 0..127
  const int sslot = (t & 3) ^ ((srow >> 1) & 3);
  const short* agA0 = As + (size_t)(row0 + srow) * Kd + sslot * 8;
  const short* agA1 = As + (size_t)(row0 + 128 + srow) * Kd + sslot * 8;
  const short* bgB0 = Bs + (size_t)(col0 + srow) * Kd + sslot * 8;
  const short* bgB1 = Bs + (size_t)(col0 + 128 + srow) * Kd + sslot * 8;

  auto stageA = [&](int buf, int kh, int kt) {
    int k0 = kt * 64 + kh * 32;
    short* base = &Als[buf][kh][0];
    gload16(agA0 + k0, base + w * 512);
    gload16(agA1 + k0, base + 4096 + w * 512);
  };
  auto stageB = [&](int buf, int kh, int kt) {
    int k0 = kt * 64 + kh * 32;
    short* base = &Bls[buf][kh][0];
    gload16(bgB0 + k0, base + w * 512);
    gload16(bgB1 + k0, base + 4096 + w * 512);
  };

  int aoff[8], boff[4];
  #pragma unroll
  for (int mf = 0; mf < 8; ++mf) {
    int r = wr * 128 + mf * 16 + lr;
    aoff[mf] = r * 32 + ((lk ^ ((r >> 1) & 3)) << 3);
  }
  #pragma unroll
  for (int nf = 0; nf < 4; ++nf) {
    int r = wc * 64 + nf * 16 + lr;
    boff[nf] = r * 32 + ((lk ^ ((r >> 1) & 3)) << 3);
  }

  f32x4 acc[8][4] = {};
  const int NT = Kd >> 6;   // K-tiles of 64

  stageA(0, 0, 0); stageA(0, 1, 0); stageB(0, 0, 0); stageB(0, 1, 0);
  asm volatile("s_waitcnt vmcnt(0)" ::: "memory");
  __builtin_amdgcn_sched_barrier(0);
  __builtin_amdgcn_s_barrier();

  for (int kt = 0; kt < NT; ++kt) {
    const int buf = kt & 1, nb = buf ^ 1;
    const short* A0 = &Als[buf][0][0];
    const short* A1 = &Als[buf][1][0];
    const short* B0 = &Bls[buf][0][0];
    const short* B1 = &Bls[buf][1][0];
    const bool st = (kt + 1 < NT);
    bf16x8 af[4], bfr[4];

    // ---- phase 1: kh0, M-half 0 ----
    #pragma unroll
    for (int i = 0; i < 4; ++i) bfr[i] = *(const bf16x8*)&B0[boff[i]];
    #pragma unroll
    for (int i = 0; i < 4; ++i) af[i]  = *(const bf16x8*)&A0[aoff[i]];
    if (st) { stageA(nb, 0, kt + 1); stageA(nb, 1, kt + 1); }
    __builtin_amdgcn_s_barrier();
    __builtin_amdgcn_s_setprio(1);
    #pragma unroll
    for (int i = 0; i < 4; ++i)
      #pragma unroll
      for (int j = 0; j < 4; ++j)
        acc[i][j] = __builtin_amdgcn_mfma_f32_16x16x32_bf16(af[i], bfr[j], acc[i][j], 0, 0, 0);
    __builtin_amdgcn_s_setprio(0);
    __builtin_amdgcn_s_barrier();

    // ---- phase 2: kh0, M-half 1 (B reused) ----
    #pragma unroll
    for (int i = 0; i < 4; ++i) af[i] = *(const bf16x8*)&A0[aoff[4 + i]];
    if (st) { stageB(nb, 0, kt + 1); stageB(nb, 1, kt + 1); }
    __builtin_amdgcn_s_barrier();
    __builtin_amdgcn_s_setprio(1);
    #pragma unroll
    for (int i = 0; i < 4; ++i)
      #pragma unroll
      for (int j = 0; j < 4; ++j)
        acc[4 + i][j] = __builtin_amdgcn_mfma_f32_16x16x32_bf16(af[i], bfr[j], acc[4 + i][j], 0, 0, 0);
    __builtin_amdgcn_s_setprio(0);
    __builtin_amdgcn_s_barrier();

    // ---- phase 3: kh1, M-half 0 ----
    #pragma unroll
    for (int i = 0; i < 4; ++i) bfr[i] = *(const bf16x8*)&B1[boff[i]];
    #pragma unroll
    for (int i = 0; i < 4; ++i) af[i]  = *(const bf16x8*)&A1[aoff[i]];
    __builtin_amdgcn_s_barrier();
    __builtin_amdgcn_s_setprio(1);
    #pragma unroll
    for (int i = 0; i < 4; ++i)
      #pragma unroll
      for (int j = 0; j < 4; ++j)
        acc[i][j] = __builtin_amdgcn_mfma_f32_16x16x32_bf16(af[i], bfr[j], acc[i][j], 0, 0, 0);
    __builtin_amdgcn_s_setprio(0);
    __builtin_amdgcn_s_barrier();

    // ---- phase 4: kh1, M-half 1 ----
    #pragma unroll
    for (int i = 0; i < 4; ++i) af[i] = *(const bf16x8*)&A1[aoff[4 + i]];
    __builtin_amdgcn_s_barrier();
    __builtin_amdgcn_s_setprio(1);
    #pragma unroll
    for (int i = 0; i < 4; ++i)
      #pragma unroll
      for (int j = 0; j < 4; ++j)
        acc[4 + i][j] = __builtin_amdgcn_mfma_f32_16x16x32_bf16(af[i], bfr[j], acc[4 + i][j], 0, 0, 0);
    __builtin_amdgcn_s_setprio(0);
    asm volatile("s_waitcnt vmcnt(0)" ::: "memory");
    __builtin_amdgcn_sched_barrier(0);
    __builtin_amdgcn_s_barrier();
  }

  #pragma unroll
  for (int mf = 0; mf < 8; ++mf)
    #pragma unroll
    for (int nf = 0; nf < 4; ++nf)
      #pragma unroll
      for (int g = 0; g < 4; ++g) {
        int r = row0 + wr * 128 + mf * 16 + lk * 4 + g;
        int c = col0 + wc * 64 + nf * 16 + lr;
        float v = acc[mf][nf][g];
        if (EPI == 5) {
          int seg = c >> 10;
          int cc = c & (BDIM - 1);
          void* dst = seg == 0 ? Cv : (seg == 1 ? Cv2 : (seg == 2 ? Cv3 : Cv4));
          if (seg < 2) {
            float xv = v + bias[cc];
            v = 0.5f * xv * (1.0f + erff(xv * 0.70710678118654752f));
          }
          ((__hip_bfloat16*)dst)[(size_t)r * BDIM + cc] = __float2bfloat16(v);
        } else {
          void* dst = Cv;
          int cc = c, ld = ldc;
          if (c >= csplit) { dst = Cv2; cc = c - csplit; ld = ldc2; }
          size_t idx = (size_t)r * ld + cc;
          float s = 1.0f / (float)((r & (TDIM - 1)) + 1);
          ((float*)dst)[idx] = v * s;
        }
      }

  // ---- fused chunk-sum for seg 3 (yW): per-thread partials + 8 atomics/thread ----
  if (EPI == 5 && (col0 >> 10) == 3) {
    #pragma unroll
    for (int half = 0; half < 2; ++half) {
      int rbase = row0 + wr * 128 + half * 64;     // 64-aligned chunk start
      int b  = rbase >> 12;                        // / TDIM
      int ch = (rbase & (TDIM - 1)) >> 6;
      #pragma unroll
      for (int nf = 0; nf < 4; ++nf) {
        float s = 0.0f;
        #pragma unroll
        for (int mf = half * 4; mf < half * 4 + 4; ++mf)
          #pragma unroll
          for (int g = 0; g < 4; ++g) s += acc[mf][nf][g];
        int j = (col0 - 3 * BDIM) + wc * 64 + nf * 16 + lr;
        atomicAdd(&Sp[((size_t)b * NCH + ch) * KRC + j], s);
      }
    }
  }
}

// ---------------- merged router + scan (both direct dependents of the big GEMM) ----------------
// blocks [0, 2048): router, 1024 thr = 16 waves, wave w handles global row blk*16+w
//   (branch = row >= BT); identical per-row math/reduction order to the 256-thr version.
// blocks [2048, 2052): exclusive scan of chunk sums, 1024 thr, unchanged.
__global__ __launch_bounds__(1024) void router_scan_kernel(
    const __hip_bfloat16* __restrict__ Hf, const __hip_bfloat16* __restrict__ Hi,
    const float* __restrict__ w2, const float* __restrict__ b2,
    const float* __restrict__ ebias, float* __restrict__ wgt_f, float* __restrict__ wgt_i,
    float* __restrict__ S) {
  int blk = blockIdx.x;
  if (blk < 2048) {
    int wv = threadIdx.x >> 6;          // 0..15
    int l  = threadIdx.x & 63;
    int gr = blk * 16 + wv;             // 0..32767
    const __hip_bfloat16* H = (gr >= BT) ? Hi : Hf;
    float* wgt = (gr >= BT) ? wgt_i : wgt_f;
    int row = gr & (BT - 1);
    const short* Hs = (const short*)H;
    float acc[KEXPN] = {};
    #pragma unroll
    for (int i = 0; i < BDIM / 512; i++) {
      int h = (i * 64 + l) * 8;
      bf16x8 hv = *(const bf16x8*)(Hs + (size_t)row * BDIM + h);
      #pragma unroll
      for (int j = 0; j < 8; j++) {
        unsigned int ui = ((unsigned int)(unsigned short)hv[j]) << 16;
        float xv = __uint_as_float(ui);
        #pragma unroll
        for (int k = 0; k < KEXPN; k++) acc[k] += xv * w2[k * BDIM + h + j];
      }
    }
    #pragma unroll
    for (int k = 0; k < KEXPN; k++)
      for (int off = 32; off; off >>= 1) acc[k] += __shfl_down(acc[k], off);
    if (l == 0) {
      float lg[KEXPN];
      float mx = -1e30f;
      #pragma unroll
      for (int k = 0; k < KEXPN; k++) { lg[k] = acc[k] + b2[k] + ebias[k]; mx = fmaxf(mx, lg[k]); }
      float s = 0.0f;
      #pragma unroll
      for (int k = 0; k < KEXPN; k++) { lg[k] = expf(lg[k] - mx); s += lg[k]; }
      float inv = 1.0f / s;
      #pragma unroll
      for (int k = 0; k < KEXPN; k++) wgt[(size_t)row * KEXPN + k] = lg[k] * inv;
    }
  } else {
    int b = blk - 2048;                 // 0..3
    int j = threadIdx.x;
    float run = 0.0f;
    for (int ch = 0; ch < NCH; ch++) {
      size_t i = ((size_t)b * NCH + ch) * KRC + j;
      float v = S[i];
      S[i] = run;
      run += v;
    }
  }
}

// ---------------- cumsum phase 3 + combine both branches -> Pcat (+ ext cols fused) ----------------
__global__ __launch_bounds__(1024) void combine_kernel(const __hip_bfloat16* __restrict__ yW,
    const float* __restrict__ S, const __hip_bfloat16* __restrict__ xV,
    const float* __restrict__ wf, const float* __restrict__ wi,
    const float* __restrict__ alphaPtr, __hip_bfloat16* __restrict__ P) {
  int j  = threadIdx.x;
  int ch = blockIdx.x;
  int b  = blockIdx.y;
  float alpha = alphaPtr[0];
  float scale = (j < KR) ? 1.0f : alpha;
  const float* wgt = (j < KR) ? wf : wi;
  int k = (j & (KR - 1)) >> 6;
  float run = S[((size_t)b * NCH + ch) * KRC + j];
  for (int t0 = 0; t0 < TC; t0++) {
    size_t row = (size_t)b * TDIM + ch * TC + t0;
    run += __bfloat162float(yW[row * KRC + j]);
    float p = __bfloat162float(xV[row * KRC + j]) * run * wgt[row * KEXPN + k] * scale;
    P[row * PW2 + j] = __float2bfloat16(p);
  }
  if (j < 128) {
    int col = KRC + j;
    for (int t0 = 0; t0 < TC; t0++) {
      size_t row = (size_t)b * TDIM + ch * TC + t0;
      float v = 0.0f;
      if (j < KEXPN)          v = wf[row * KEXPN + j];
      else if (j < 2 * KEXPN) v = wi[row * KEXPN + (j - KEXPN)] * alpha;
      P[row * PW2 + col] = __float2bfloat16(v);
    }
  }
}

// ---------------- sentinel ----------------
__global__ __launch_bounds__(256) void fill_kernel(float* __restrict__ out, long n, float val) {
  long id = (long)blockIdx.x * 256 + threadIdx.x;
  if (id < n) out[id] = val;
}

extern "C" void kernel_launch(void* const* d_in, const int* in_sizes, int n_in,
                              void* d_out, int out_size, void* d_ws, size_t ws_size,
                              hipStream_t stream) {
  const float* x        = (const float*)d_in[0];
  const float* W_Q      = (const float*)d_in[1];
  const float* W_K      = (const float*)d_in[2];
  const float* W_O      = (const float*)d_in[3];
  const float* W_inv    = (const float*)d_in[4];
  const float* V_fwd    = (const float*)d_in[5];
  const float* W_fwd    = (const float*)d_in[6];
  const float* U_fwd    = (const float*)d_in[7];
  const float* b_fwd    = (const float*)d_in[8];
  const float* V_inv    = (const float*)d_in[9];
  const float* W_inv_e  = (const float*)d_in[10];
  const float* U_inv    = (const float*)d_in[11];
  const float* b_inv    = (const float*)d_in[12];
  const float* rw1      = (const float*)d_in[13];
  const float* rb1      = (const float*)d_in[14];
  const float* rw2      = (const float*)d_in[15];
  const float* rb2      = (const float*)d_in[16];
  const float* alphaPtr = (const float*)d_in[17];
  const float* ebias    = (const float*)d_in[18];

  char* ws = (char*)d_ws;
  size_t off = 0;
  auto alloc = [&](size_t sz) -> void* {
    void* p = ws + off;
    off += (sz + 255) & ~(size_t)255;
    return p;
  };

  const size_t RB = (size_t)BDIM * 2;
  void* winvT = alloc((size_t)BDIM * RB);
  void* wqT   = alloc((size_t)BDIM * RB);
  void* wkT   = alloc((size_t)BDIM * RB);
  void* wo    = alloc((size_t)BDIM * RB);
  void* ST    = alloc((size_t)2048 * RB);
  void* HXQ   = alloc((size_t)3072 * RB);
  void* XKA   = alloc((size_t)1024 * RB);
  void* BigB  = alloc((size_t)4096 * RB);
  void* UTT   = alloc((size_t)PW2 * RB);
  void* Mcat  = alloc((size_t)BDIM * PW2 * 2);
  void* wgt_f = alloc((size_t)BT * KEXPN * 4);
  void* wgt_i = alloc((size_t)BT * KEXPN * 4);
  void* S     = alloc((size_t)4 * NCH * KRC * 4);
  void* s_x   = alloc((size_t)BT * BDIM * 2);
  void* Hf    = alloc((size_t)BT * BDIM * 2);
  void* Hi    = alloc((size_t)BT * BDIM * 2);
  void* xVcat = alloc((size_t)BT * KRC * 2);
  void* yWcat = alloc((size_t)BT * KRC * 2);
  void* Pcat  = Hf;

  if (off > ws_size) {
    fill_kernel<<<dim3((unsigned)((out_size + 255) / 256)), 256, 0, stream>>>(
        (float*)d_out, (long)out_size, (float)(off >> 20));
    return;
  }

  __hip_bfloat16* STp  = (__hip_bfloat16*)ST;
  __hip_bfloat16* HXQp = (__hip_bfloat16*)HXQ;
  __hip_bfloat16* XKAp = (__hip_bfloat16*)XKA;
  __hip_bfloat16* BigBp= (__hip_bfloat16*)BigB;
  __hip_bfloat16* UTTp = (__hip_bfloat16*)UTT;

  auto gemm2b = [&](const void* A, const void* Bm, void* C, void* C2, void* C3, void* C4,
                    int csplit, int ldc, int ldc2, int M, int N, int Kd, int epi,
                    const float* bias) {
    dim3 g(N / 256, M / 256);
    if (epi == 5) gemm_nt_256<5><<<g, 512, 0, stream>>>((const __hip_bfloat16*)A, (const __hip_bfloat16*)Bm, C, C2, C3, C4, csplit, ldc, ldc2, bias, (float*)S, M, N, Kd);
    else          gemm_nt_256<4><<<g, 512, 0, stream>>>((const __hip_bfloat16*)A, (const __hip_bfloat16*)Bm, C, C2, C3, C4, csplit, ldc, ldc2, bias, (float*)S, M, N, Kd);
  };

  // ---- ONE merged prep launch (13 partitioned jobs, incl. S zeroing) ----
  mega_prep_kernel<<<dim3(PB12), 256, 0, stream>>>(
      x, (__hip_bfloat16*)s_x, W_O, (__hip_bfloat16*)wo, rw1, STp, HXQp,
      W_inv, (__hip_bfloat16*)winvT, W_Q, (__hip_bfloat16*)wqT, W_K, (__hip_bfloat16*)wkT,
      V_fwd, W_fwd, W_inv_e, V_inv, XKAp,
      U_fwd, b_fwd, U_inv, b_inv, UTTp, (float*)S);

  // ---- folds: 2 launches, 2 parallel partitions each ----
  {
    FoldArgs f0 = { STp, (const __hip_bfloat16*)winvT,
                    HXQp + (size_t)1024 * BDIM, HXQp + (size_t)2560 * BDIM,
                    XKAp + (size_t)512 * BDIM, 1024, 1536, BDIM, 2048, BDIM, BDIM };
    FoldArgs f1 = { (const __hip_bfloat16*)wo, UTTp,
                    Mcat, nullptr, nullptr, 1 << 30, 1 << 30, PW2, BDIM, PW2, BDIM };
    int n0 = (f0.M / 128) * (f0.N / 128);
    int n1 = (f1.M / 128) * (f1.N / 128);
    gemm_fold2<<<dim3(n0 + n1), 256, 0, stream>>>(f0, f1, n0);
  }
  {
    FoldArgs f0 = { HXQp, (const __hip_bfloat16*)wqT,
                    BigBp, nullptr, nullptr, 1 << 30, 1 << 30, BDIM, 3072, BDIM, BDIM };
    FoldArgs f1 = { XKAp, (const __hip_bfloat16*)wkT,
                    BigBp + (size_t)3072 * BDIM, nullptr, nullptr, 1 << 30, 1 << 30,
                    BDIM, 1024, BDIM, BDIM };
    int n0 = (f0.M / 128) * (f0.N / 128);
    int n1 = (f1.M / 128) * (f1.N / 128);
    gemm_fold2<<<dim3(n0 + n1), 256, 0, stream>>>(f0, f1, n0);
  }

  // ---- ONE merged big GEMM: [Hf|Hi|xVcat|yWcat] = x @ BigB^T (N=4096, EPI=5 + chunksum) ----
  gemm2b(s_x, BigB, Hf, Hi, xVcat, yWcat, 0, 0, 0, BT, 4 * BDIM, BDIM, 5, rb1);

  // ---- merged router + scan (one launch) ----
  router_scan_kernel<<<dim3(2048 + 4), 1024, 0, stream>>>(
      (const __hip_bfloat16*)Hf, (const __hip_bfloat16*)Hi, rw2, rb2, ebias,
      (float*)wgt_f, (float*)wgt_i, (float*)S);

  // ---- combine into Pcat ----
  dim3 gch(NCH, 4);
  combine_kernel<<<gch, 1024, 0, stream>>>((const __hip_bfloat16*)yWcat, (const float*)S,
      (const __hip_bfloat16*)xVcat, (const float*)wgt_f, (const float*)wgt_i,
      alphaPtr, (__hip_bfloat16*)Pcat);

  // ---- single output GEMM: out = diag(1/n) * Pcat @ Mcat^T (K=1152) ----
  gemm2b(Pcat, Mcat, d_out, d_out, nullptr, nullptr, BDIM, BDIM, BDIM,
         BT, BDIM, PW2, 4, nullptr);
}